// Round 12
// baseline (216.311 us; speedup 1.0000x reference)
//
#include <hip/hip_runtime.h>
#include <hip/hip_bf16.h>

#define CDIM   1024
#define NHEADS 16
#define DHEAD  64
#define BATCH  4
#define TSEQ   2048
#define MROWS  (BATCH * TSEQ)
#define QSTR   3072                /* fused qkv row stride */
#define NEG_BIG (-1e30f)
#define MASKVAL (-3.0e38f)
#define SCALE_L2E 0.18033688011f   /* 0.125 * log2(e) */
#define DEFER_TH 11.5416f          /* 8 nats in log2 units */

typedef __attribute__((ext_vector_type(8)))  short bf16x8;
typedef __attribute__((ext_vector_type(4)))  float f32x4;
typedef __attribute__((ext_vector_type(16))) float f32x16;

__device__ __forceinline__ unsigned short f2bf(float f) {
    __hip_bfloat16 h = __float2bfloat16(f);
    return *reinterpret_cast<unsigned short*>(&h);
}
__device__ __forceinline__ unsigned int cvtpk(float a, float b) {
    unsigned r;
    asm("v_cvt_pk_bf16_f32 %0, %1, %2" : "=v"(r) : "v"(a), "v"(b));
    return r;   // lo = bf16(a), hi = bf16(b)
}
__device__ __forceinline__ float ex2(float x) {   // raw v_exp_f32 (exp2)
    float r; asm("v_exp_f32 %0, %1" : "=v"(r) : "v"(x)); return r;
}

// ---------------- x: fp32 -> bf16 (8 elems/thread) --------------------------
__global__ __launch_bounds__(256)
void cvt_x_kernel(const float* __restrict__ in, unsigned short* __restrict__ out)
{
    size_t i = (size_t)blockIdx.x * 256 + threadIdx.x;
    const float4* p = reinterpret_cast<const float4*>(in) + i * 2;
    float4 a = p[0], b = p[1];
    uint4 o;
    o.x = (unsigned)f2bf(a.x) | ((unsigned)f2bf(a.y) << 16);
    o.y = (unsigned)f2bf(a.z) | ((unsigned)f2bf(a.w) << 16);
    o.z = (unsigned)f2bf(b.x) | ((unsigned)f2bf(b.y) << 16);
    o.w = (unsigned)f2bf(b.z) | ((unsigned)f2bf(b.w) << 16);
    *reinterpret_cast<uint4*>(out + i * 8) = o;
}

// ---------------- W[K][N] fp32 -> W^T[N][K] bf16 (32x32 LDS tiles) ----------
__global__ __launch_bounds__(256)
void wt_kernel(const float* __restrict__ W0, const float* __restrict__ W1,
               const float* __restrict__ W2, const float* __restrict__ W3,
               unsigned short* __restrict__ T0, unsigned short* __restrict__ T1,
               unsigned short* __restrict__ T2, unsigned short* __restrict__ T3)
{
    const float* W; unsigned short* T;
    switch (blockIdx.z) {
        case 0:  W = W0; T = T0; break;
        case 1:  W = W1; T = T1; break;
        case 2:  W = W2; T = T2; break;
        default: W = W3; T = T3; break;
    }
    __shared__ float tile[32][33];
    const int t = threadIdx.x;
    const int r = t >> 3;
    const int c4 = (t & 7) * 4;
    const int n0 = blockIdx.x * 32, k0 = blockIdx.y * 32;
    float4 v = *reinterpret_cast<const float4*>(&W[(size_t)(k0 + r) * CDIM + n0 + c4]);
    tile[r][c4 + 0] = v.x; tile[r][c4 + 1] = v.y;
    tile[r][c4 + 2] = v.z; tile[r][c4 + 3] = v.w;
    __syncthreads();
    uint2 o;
    o.x = (unsigned)f2bf(tile[c4 + 0][r]) | ((unsigned)f2bf(tile[c4 + 1][r]) << 16);
    o.y = (unsigned)f2bf(tile[c4 + 2][r]) | ((unsigned)f2bf(tile[c4 + 3][r]) << 16);
    *reinterpret_cast<uint2*>(&T[(size_t)(n0 + r) * CDIM + k0 + c4]) = o;
}

// ---------------- bias concat [bq|bk|bv] ------------------------------------
__global__ __launch_bounds__(256)
void pack_bias(const float* __restrict__ bq, const float* __restrict__ bk,
               const float* __restrict__ bv, float* __restrict__ o)
{
    int i = blockIdx.x * 256 + threadIdx.x;   // 0..3071
    float v = (i < 1024) ? bq[i] : (i < 2048 ? bk[i - 1024] : bv[i - 2048]);
    o[i] = v;
}

// ================= 8-phase 256x256 deep-pipelined GEMM (T2+T3+T4+T5) ========
#define GBAR8  asm volatile("s_barrier" ::: "memory")
#define LGKM0  asm volatile("s_waitcnt lgkmcnt(0)" ::: "memory")
#define VMC4   asm volatile("s_waitcnt vmcnt(4)" ::: "memory")
#define VMC0   asm volatile("s_waitcnt vmcnt(0)" ::: "memory")

#define STAGE8(dsthalf, srcp) do { \
    __builtin_amdgcn_global_load_lds( \
        (const __attribute__((address_space(1))) void*)(srcp), \
        (__attribute__((address_space(3))) void*)((dsthalf) + wv * 1024), 16, 0, 0); \
    __builtin_amdgcn_global_load_lds( \
        (const __attribute__((address_space(1))) void*)((srcp) + 65536), \
        (__attribute__((address_space(3))) void*)((dsthalf) + 8192 + wv * 1024), 16, 0, 0); \
} while (0)

#define LDA8(grp) do { \
    _Pragma("unroll") for (int m_ = 0; m_ < 4; ++m_) { \
        const int rl_ = (grp) * 64 + m_ * 16 + lj; \
        _Pragma("unroll") for (int k_ = 0; k_ < 2; ++k_) \
            af[m_][k_] = *reinterpret_cast<const bf16x8*>( \
                Ab + rl_ * 128 + (((k_ * 4 + lg) ^ (lj & 7)) * 16)); \
    } } while (0)

#define LDB8(pairi) do { \
    _Pragma("unroll") for (int n_ = 0; n_ < 2; ++n_) { \
        const int nr_ = (pairi) * 2 + n_; \
        const int rl_ = (wc & 1) * 64 + nr_ * 16 + lj; \
        _Pragma("unroll") for (int k_ = 0; k_ < 2; ++k_) \
            bfr[nr_][k_] = *reinterpret_cast<const bf16x8*>( \
                Bb + rl_ * 128 + (((k_ * 4 + lg) ^ (lj & 7)) * 16)); \
    } } while (0)

#define MM8(mg, npair) do { \
    __builtin_amdgcn_s_setprio(1); \
    _Pragma("unroll") for (int m_ = 0; m_ < 4; ++m_) \
        _Pragma("unroll") for (int n_ = 0; n_ < 2; ++n_) \
            _Pragma("unroll") for (int k_ = 0; k_ < 2; ++k_) \
                acc[(mg) * 4 + m_][(npair) * 2 + n_] = \
                    __builtin_amdgcn_mfma_f32_16x16x32_bf16( \
                        af[m_][k_], bfr[(npair) * 2 + n_][k_], \
                        acc[(mg) * 4 + m_][(npair) * 2 + n_], 0, 0, 0); \
    __builtin_amdgcn_s_setprio(0); \
} while (0)

__global__ __launch_bounds__(512)
void gemm_8ph(const unsigned short* __restrict__ A,
              const unsigned short* __restrict__ BT,
              const float* __restrict__ bias,
              unsigned short* __restrict__ Cout, int N, int nScaled)
{
    __shared__ __align__(16) char lds8[2][65536];
    const int tid = threadIdx.x;
    const int nbn = N >> 8;
    const int bid = blockIdx.x;
    const int wg  = (bid & 7) * ((int)gridDim.x >> 3) + (bid >> 3);  // XCD swizzle
    const int n0  = (wg % nbn) * 256;
    const int m0  = (wg / nbn) * 256;

    const int lane = tid & 63, wv = tid >> 6;
    const int wr = wv >> 2, wc = wv & 3;
    const int lj = lane & 15, lg = lane >> 4;
    const int srow = tid >> 3;
    const int gsw  = 8 * ((tid & 7) ^ ((tid >> 3) & 7));

    char* buf0 = &lds8[0][0];
    char* buf1 = &lds8[1][0];

    const unsigned short* Alo = A  + (size_t)(m0 + srow) * 1024 + gsw;
    const unsigned short* Ahi = A  + (size_t)(m0 + 128 + srow) * 1024 + gsw;
    const unsigned short* Blo = BT + (size_t)(n0 + srow) * 1024 + gsw;
    const unsigned short* Bhi = BT + (size_t)(n0 + 128 + srow) * 1024 + gsw;

    f32x4 acc[8][4];
    #pragma unroll
    for (int i = 0; i < 8; ++i)
        #pragma unroll
        for (int j = 0; j < 4; ++j) acc[i][j] = f32x4{0.f, 0.f, 0.f, 0.f};

    STAGE8(buf0 + 0,     Alo);
    STAGE8(buf0 + 16384, Ahi);
    STAGE8(buf0 + 32768, Blo);
    STAGE8(buf0 + 49152, Bhi);
    STAGE8(buf1 + 32768, Blo + 64);
    STAGE8(buf1 + 49152, Bhi + 64);
    VMC0; GBAR8;

    bf16x8 af[4][2], bfr[4][2];

    for (int it = 0; it < 8; ++it) {
        const int e = 2 * it, o = e + 1;
        const bool se = (e + 2) < 16;
        const bool so = (o + 2) < 16;

        char* Ab = buf0 + wr * 16384;
        char* Bb = buf0 + 32768 + (wc >> 1) * 16384;
        LDA8(0); LDB8(0);
        STAGE8(buf1 + 0, Alo + o * 64);
        GBAR8; LGKM0; MM8(0, 0); GBAR8;
        LDB8(1);
        STAGE8(buf1 + 16384, Ahi + o * 64);
        GBAR8; LGKM0; MM8(0, 1); GBAR8;
        LDA8(1);
        if (se) STAGE8(buf0 + 32768, Blo + (e + 2) * 64);
        GBAR8; LGKM0; MM8(1, 0); GBAR8;
        if (se) STAGE8(buf0 + 49152, Bhi + (e + 2) * 64);
        GBAR8; LGKM0; MM8(1, 1);
        if (se) { VMC4; } else { VMC0; }
        GBAR8;

        Ab = buf1 + wr * 16384;
        Bb = buf1 + 32768 + (wc >> 1) * 16384;
        LDA8(0); LDB8(0);
        if (se) STAGE8(buf0 + 0, Alo + (e + 2) * 64);
        GBAR8; LGKM0; MM8(0, 0); GBAR8;
        LDB8(1);
        if (se) STAGE8(buf0 + 16384, Ahi + (e + 2) * 64);
        GBAR8; LGKM0; MM8(0, 1); GBAR8;
        LDA8(1);
        if (so) STAGE8(buf1 + 32768, Blo + (o + 2) * 64);
        GBAR8; LGKM0; MM8(1, 0); GBAR8;
        if (so) STAGE8(buf1 + 49152, Bhi + (o + 2) * 64);
        GBAR8; LGKM0; MM8(1, 1);
        if (so) { VMC4; } else { VMC0; }
        GBAR8;
    }

    const float sc = (n0 < nScaled) ? SCALE_L2E : 1.0f;
    float bcol[4];
    #pragma unroll
    for (int nr = 0; nr < 4; ++nr) bcol[nr] = bias[n0 + wc * 64 + nr * 16 + lj];

    #pragma unroll
    for (int mr = 0; mr < 8; ++mr) {
        #pragma unroll
        for (int r4 = 0; r4 < 4; ++r4) {
            const int row = m0 + wr * 128 + mr * 16 + lg * 4 + r4;
            #pragma unroll
            for (int nr = 0; nr < 4; ++nr) {
                const int col = n0 + wc * 64 + nr * 16 + lj;
                Cout[(size_t)row * N + col] = f2bf((acc[mr][nr][r4] + bcol[nr]) * sc);
            }
        }
    }
}

// ---------------- m97-structure GEMM, BK=64 (P-projection) ------------------
template<int OUTMODE>
__global__ __launch_bounds__(256)
void gemm_glds(const unsigned short* __restrict__ A,
               const unsigned short* __restrict__ BT,
               const float* __restrict__ bias,
               void* __restrict__ Cout, int M, int N, int K, int nScaled)
{
    __shared__ __align__(16) unsigned short As[128 * 64];   // 16KB
    __shared__ __align__(16) unsigned short Bs[128 * 64];
    const int tid = threadIdx.x;
    const int nbn = N >> 7;
    const int bid = blockIdx.x;
    const int wg  = (bid & 7) * ((int)gridDim.x >> 3) + (bid >> 3);  // XCD swizzle
    const int n0  = (wg % nbn) * 128;
    const int m0  = (wg / nbn) * 128;

    const int lane = tid & 63, w = tid >> 6;
    const int wr = w >> 1, wc = w & 1;
    const int lj = lane & 15, lg = lane >> 4;
    const int srow = w * 8 + (lane >> 3);
    const int gsw  = 8 * ((lane & 7) ^ (lane >> 3));

    char* AsB = (char*)As;
    char* BsB = (char*)Bs;

    f32x4 acc[4][4];
    #pragma unroll
    for (int i = 0; i < 4; ++i)
        #pragma unroll
        for (int j = 0; j < 4; ++j) acc[i][j] = f32x4{0.f, 0.f, 0.f, 0.f};

    for (int k0 = 0; k0 < K; k0 += 64) {
        __syncthreads();
        #pragma unroll
        for (int ra = 0; ra < 4; ++ra) {
            const int r = ra * 32 + srow;
            __builtin_amdgcn_global_load_lds(
                (const __attribute__((address_space(1))) void*)(A + (size_t)(m0 + r) * K + k0 + gsw),
                (__attribute__((address_space(3))) void*)(AsB + ra * 4096 + w * 1024),
                16, 0, 0);
            __builtin_amdgcn_global_load_lds(
                (const __attribute__((address_space(1))) void*)(BT + (size_t)(n0 + r) * K + k0 + gsw),
                (__attribute__((address_space(3))) void*)(BsB + ra * 4096 + w * 1024),
                16, 0, 0);
        }
        __syncthreads();
        #pragma unroll
        for (int ks = 0; ks < 2; ++ks) {
            bf16x8 af[4], bfr[4];
            #pragma unroll
            for (int i = 0; i < 4; ++i) {
                const int r = wr * 64 + i * 16 + lj;
                af[i] = *reinterpret_cast<const bf16x8*>(
                    AsB + r * 128 + (((ks * 4 + lg) ^ (lj & 7)) * 16));
            }
            #pragma unroll
            for (int j = 0; j < 4; ++j) {
                const int r = wc * 64 + j * 16 + lj;
                bfr[j] = *reinterpret_cast<const bf16x8*>(
                    BsB + r * 128 + (((ks * 4 + lg) ^ (lj & 7)) * 16));
            }
            #pragma unroll
            for (int i = 0; i < 4; ++i)
                #pragma unroll
                for (int j = 0; j < 4; ++j)
                    acc[i][j] = __builtin_amdgcn_mfma_f32_16x16x32_bf16(af[i], bfr[j], acc[i][j], 0, 0, 0);
        }
    }

    const float sc = (n0 < nScaled) ? SCALE_L2E : 1.0f;
    float bcol[4];
    #pragma unroll
    for (int j = 0; j < 4; ++j) bcol[j] = bias[n0 + wc * 64 + j * 16 + lj];

    #pragma unroll
    for (int i = 0; i < 4; ++i) {
        #pragma unroll
        for (int r4 = 0; r4 < 4; ++r4) {
            const int row = m0 + wr * 64 + i * 16 + lg * 4 + r4;
            #pragma unroll
            for (int j = 0; j < 4; ++j) {
                const int col = n0 + wc * 64 + j * 16 + lj;
                float v = (acc[i][j][r4] + bcol[j]) * sc;
                if (OUTMODE == 0)
                    reinterpret_cast<unsigned short*>(Cout)[(size_t)row * N + col] = f2bf(v);
                else
                    reinterpret_cast<float*>(Cout)[(size_t)row * N + col] = v;
            }
        }
    }
}

// ---------------- MFMA flash attention, KVBLK=128 (R9 skeleton) -------------
// 512 blocks, 4 waves x 32 q-rows = 128-row q-tile; balanced pair (p, 15-p)
// sequentially, now 17 uniform 128-key iterations (was 34 x 64-key).
// XCD-grouped id mapping (R5-verified). Same 2-barrier sync skeleton + reg
// prefetch of kt+1 as the verified R9 kernel; only the tile K-extent doubled
// (halves barrier/staging fixed overheads, doubles MFMA cluster).
// DO NOT add __launch_bounds__ min-waves (R8 spill lesson). VGPR est ~190;
// occupancy is grid-capped at 2 waves/SIMD so VGPR<=256 costs nothing.
#define PV_STEP9(m, T, rb) { \
    unsigned int w01 = cvtpk(T[(rb)+0], T[(rb)+1]); \
    unsigned int w23 = cvtpk(T[(rb)+2], T[(rb)+3]); \
    unsigned int w45 = cvtpk(T[(rb)+4], T[(rb)+5]); \
    unsigned int w67 = cvtpk(T[(rb)+6], T[(rb)+7]); \
    asm("v_permlane32_swap_b32 %0, %1" : "+v"(w01), "+v"(w45)); \
    asm("v_permlane32_swap_b32 %0, %1" : "+v"(w23), "+v"(w67)); \
    union { unsigned int u[4]; bf16x8 v; } pa; \
    pa.u[0] = w01; pa.u[1] = w23; pa.u[2] = w45; pa.u[3] = w67; \
    const int voff = (32 * (m) + 16 * hi) ^ lqswz; \
    bf16x8 va = *reinterpret_cast<const bf16x8*>(VTB + lq * 256 + voff); \
    bf16x8 vb = *reinterpret_cast<const bf16x8*>(VTB + (lq + 32) * 256 + voff); \
    y0 = __builtin_amdgcn_mfma_f32_32x32x16_bf16(va, pa.v, y0, 0, 0, 0); \
    y1 = __builtin_amdgcn_mfma_f32_32x32x16_bf16(vb, pa.v, y1, 0, 0, 0); \
}

__global__ __launch_bounds__(256)
void attn_mfma9(const unsigned short* __restrict__ QKV, unsigned short* __restrict__ Yb)
{
    __shared__ unsigned short Ks[128 * 64];   // [key][d], swizzled, 16KB
    __shared__ unsigned short VTs[64 * 128];  // [d][key], swizzled, 16KB
    __shared__ unsigned short Ysc[4][32 * 72];// per-wave [q][d], 144B stride

    const int tid = threadIdx.x, lane = tid & 63, wid = tid >> 6;
    const int lq = lane & 31, hi = lane >> 5;
    const int lqswz = (lq & 7) << 4;

    // XCD-grouped decomposition: id%8 == hb%8 -> same (h,b) shares an XCD
    const int id  = blockIdx.x;
    const int kk  = id >> 3;
    const int hb  = (id & 7) + 8 * (kk >> 3);
    const int pair = kk & 7;
    const int h = hb & 15, bz = hb >> 4;

    const size_t rowbase = (size_t)bz * TSEQ;
    const int hq = h * DHEAD, hk = 1024 + h * DHEAD, hv = 2048 + h * DHEAD;
    char* KsB = (char*)Ks;
    char* VTB = (char*)VTs;

    // staging thread mapping (constant per thread)
    const int krow  = tid >> 3;            // K rows krow + 32p, p=0..3
    const int kcol8 = (tid & 7) * 8;
    const int kswz  = ((tid & 7) * 16) ^ ((krow & 7) << 4);
    const int vk2   = 2 * (tid & 63);      // V key-pair 0..126
    const int vdg   = (tid >> 6) * 8;      // V d-group {0,8,16,24} (+32 second half)
    const int vkb   = vk2 * 2;             // byte offset of pair

    for (int iter = 0; iter < 2; ++iter) {
        const int qtile = iter ? (15 - pair) : pair;
        const int q0 = qtile * 128;
        const int wq = q0 + wid * 32;

        bf16x8 qf[4];                            // Q^T B-frags: d = 16s + 8hi + j
        {
            const unsigned short* qp = QKV + (rowbase + wq + lq) * QSTR + hq + hi * 8;
            #pragma unroll
            for (int s = 0; s < 4; ++s)
                qf[s] = *reinterpret_cast<const bf16x8*>(qp + s * 16);
        }
        f32x16 y0, y1;                           // Y^T tiles: d 0..31 / 32..63
        #pragma unroll
        for (int r = 0; r < 16; ++r) { y0[r] = 0.f; y1[r] = 0.f; }
        float mrow = NEG_BIG, lrow = 0.f;

        const int ktend = qtile + 1;             // 128-key tiles

        // prefetch tile 0 into registers
        uint4 kr[4], vr[4];
        {
            const unsigned short* kp = QKV + (rowbase + krow) * QSTR + hk + kcol8;
            #pragma unroll
            for (int p = 0; p < 4; ++p)
                kr[p] = *reinterpret_cast<const uint4*>(kp + 32 * p * QSTR);
            const unsigned short* vp = QKV + (rowbase + vk2) * QSTR + hv + vdg;
            vr[0] = *reinterpret_cast<const uint4*>(vp);
            vr[1] = *reinterpret_cast<const uint4*>(vp + QSTR);
            vr[2] = *reinterpret_cast<const uint4*>(vp + 32);
            vr[3] = *reinterpret_cast<const uint4*>(vp + QSTR + 32);
        }

        for (int kt = 0; kt < ktend; ++kt) {
            __syncthreads();                     // previous tile's consumers done
            // ---- write prefetched regs -> LDS (K swizzled, V^T perm-packed)
            #pragma unroll
            for (int p = 0; p < 4; ++p)
                *reinterpret_cast<uint4*>(KsB + (krow + 32 * p) * 128 + kswz) = kr[p];
            #pragma unroll
            for (int half = 0; half < 2; ++half) {
                unsigned short a8[8], b8[8];
                *reinterpret_cast<uint4*>(a8) = vr[2 * half];
                *reinterpret_cast<uint4*>(b8) = vr[2 * half + 1];
                const int dbase = vdg + 32 * half;
                #pragma unroll
                for (int i2 = 0; i2 < 8; ++i2) {
                    unsigned int w = (unsigned)a8[i2] | ((unsigned)b8[i2] << 16);
                    const int d = dbase + i2;
                    *reinterpret_cast<unsigned*>(VTB + d * 256 + (vkb ^ ((d & 7) << 4))) = w;
                }
            }
            __syncthreads();                     // LDS tile ready

            // ---- issue next tile's global loads (latency hides under compute)
            if (kt + 1 < ktend) {
                const unsigned short* kp = QKV + (rowbase + (kt + 1) * 128 + krow) * QSTR + hk + kcol8;
                #pragma unroll
                for (int p = 0; p < 4; ++p)
                    kr[p] = *reinterpret_cast<const uint4*>(kp + 32 * p * QSTR);
                const unsigned short* vp = QKV + (rowbase + (kt + 1) * 128 + vk2) * QSTR + hv + vdg;
                vr[0] = *reinterpret_cast<const uint4*>(vp);
                vr[1] = *reinterpret_cast<const uint4*>(vp + QSTR);
                vr[2] = *reinterpret_cast<const uint4*>(vp + 32);
                vr[3] = *reinterpret_cast<const uint4*>(vp + QSTR + 32);
            }

            if (kt * 128 > wq + 31) continue;    // tile fully above diagonal

            // ---- S^T = K Q^T (16 mfma 32x32x16); scale pre-folded into Q
            f32x16 s0, s1, s2, s3;
            #pragma unroll
            for (int r = 0; r < 16; ++r) { s0[r] = 0.f; s1[r] = 0.f; s2[r] = 0.f; s3[r] = 0.f; }
            #pragma unroll
            for (int ss = 0; ss < 4; ++ss) {
                const int off = (ss * 32 + hi * 16) ^ lqswz;
                bf16x8 k0 = *reinterpret_cast<const bf16x8*>(KsB + lq * 128 + off);
                bf16x8 k1 = *reinterpret_cast<const bf16x8*>(KsB + (lq + 32) * 128 + off);
                bf16x8 k2 = *reinterpret_cast<const bf16x8*>(KsB + (lq + 64) * 128 + off);
                bf16x8 k3 = *reinterpret_cast<const bf16x8*>(KsB + (lq + 96) * 128 + off);
                s0 = __builtin_amdgcn_mfma_f32_32x32x16_bf16(k0, qf[ss], s0, 0, 0, 0);
                s1 = __builtin_amdgcn_mfma_f32_32x32x16_bf16(k1, qf[ss], s1, 0, 0, 0);
                s2 = __builtin_amdgcn_mfma_f32_32x32x16_bf16(k2, qf[ss], s2, 0, 0, 0);
                s3 = __builtin_amdgcn_mfma_f32_32x32x16_bf16(k3, qf[ss], s3, 0, 0, 0);
            }

            // ---- causal mask (diagonal tiles only)
            const bool diag = (kt * 128 + 127) > wq;
            if (diag) {
                const int q_own = wq + lq;
                #pragma unroll
                for (int r = 0; r < 16; ++r) {
                    const int kl = kt * 128 + (r & 3) + 8 * (r >> 2) + 4 * hi;
                    if (kl      > q_own) s0[r] = MASKVAL;
                    if (kl + 32 > q_own) s1[r] = MASKVAL;
                    if (kl + 64 > q_own) s2[r] = MASKVAL;
                    if (kl + 96 > q_own) s3[r] = MASKVAL;
                }
            }

            // ---- tree row max (64 values) + pair exchange
            float t8[8];
            #pragma unroll
            for (int r = 0; r < 8; ++r) {
                float a = fmaxf(fmaxf(s0[r], s0[r + 8]), fmaxf(s1[r], s1[r + 8]));
                float b = fmaxf(fmaxf(s2[r], s2[r + 8]), fmaxf(s3[r], s3[r + 8]));
                t8[r] = fmaxf(a, b);
            }
            #pragma unroll
            for (int r = 0; r < 4; ++r) t8[r] = fmaxf(t8[r], t8[r + 4]);
            float pm = fmaxf(fmaxf(t8[0], t8[1]), fmaxf(t8[2], t8[3]));
            pm = fmaxf(pm, __shfl_xor(pm, 32));

            // ---- defer-max rescale (T13)
            if (__any(pm > mrow + DEFER_TH)) {
                const float mnew = fmaxf(mrow, pm);
                const float alpha = ex2(mrow - mnew);
                #pragma unroll
                for (int r = 0; r < 16; ++r) { y0[r] *= alpha; y1[r] *= alpha; }
                lrow *= alpha;
                mrow = mnew;
            }
            // ---- exp2 + tree row sum
            #pragma unroll
            for (int r = 0; r < 16; ++r) {
                s0[r] = ex2(s0[r] - mrow);
                s1[r] = ex2(s1[r] - mrow);
                s2[r] = ex2(s2[r] - mrow);
                s3[r] = ex2(s3[r] - mrow);
            }
            float a8[8];
            #pragma unroll
            for (int r = 0; r < 8; ++r)
                a8[r] = ((s0[r] + s0[r + 8]) + (s1[r] + s1[r + 8]))
                      + ((s2[r] + s2[r + 8]) + (s3[r] + s3[r + 8]));
            #pragma unroll
            for (int r = 0; r < 4; ++r) a8[r] += a8[r + 4];
            float sum = (a8[0] + a8[1]) + (a8[2] + a8[3]);
            sum += __shfl_xor(sum, 32);
            lrow += sum;

            // ---- Y^T += V^T P^T (16 mfma); P^T frags via cvt_pk+permlane32_swap
            PV_STEP9(0, s0, 0)
            PV_STEP9(1, s0, 8)
            PV_STEP9(2, s1, 0)
            PV_STEP9(3, s1, 8)
            PV_STEP9(4, s2, 0)
            PV_STEP9(5, s2, 8)
            PV_STEP9(6, s3, 0)
            PV_STEP9(7, s3, 8)
        }

        // ---- epilogue: normalize, transpose via per-wave LDS, coalesced store
        {
            const float inv = 1.f / lrow;
            char* ysb = (char*)&Ysc[wid][0];
            #pragma unroll
            for (int t = 0; t < 8; ++t) {
                const int dl = ((2 * t) & 3) + 8 * (t >> 1) + 4 * hi;
                unsigned int wa = cvtpk(y0[2 * t] * inv, y0[2 * t + 1] * inv);
                unsigned int wb = cvtpk(y1[2 * t] * inv, y1[2 * t + 1] * inv);
                *reinterpret_cast<unsigned int*>(ysb + lq * 144 + dl * 2) = wa;
                *reinterpret_cast<unsigned int*>(ysb + lq * 144 + (dl + 32) * 2) = wb;
            }
            #pragma unroll
            for (int u = 0; u < 4; ++u) {
                const int rr = lane >> 1, ch = (lane & 1) + 2 * u;
                uint4 val = *reinterpret_cast<const uint4*>(ysb + rr * 144 + ch * 16);
                *reinterpret_cast<uint4*>(Yb + (rowbase + q0 + wid * 32 + rr) * CDIM + h * DHEAD + ch * 8) = val;
            }
        }
    }
}

// ---------------------------------------------------------------------------
extern "C" void kernel_launch(void* const* d_in, const int* in_sizes, int n_in,
                              void* d_out, int out_size, void* d_ws, size_t ws_size,
                              hipStream_t stream)
{
    const float* x  = (const float*)d_in[0];
    const float* Wk = (const float*)d_in[1];
    const float* bk = (const float*)d_in[2];
    const float* Wq = (const float*)d_in[3];
    const float* bq = (const float*)d_in[4];
    const float* Wv = (const float*)d_in[5];
    const float* bv = (const float*)d_in[6];
    const float* Wp = (const float*)d_in[7];
    const float* bp = (const float*)d_in[8];

    const size_t xe = (size_t)MROWS * CDIM;   // 8,388,608
    const size_t we = (size_t)CDIM * CDIM;    // 1,048,576
    unsigned short* xb    = (unsigned short*)d_ws;
    unsigned short* wqkvt = xb + xe;          // [3072][1024] = Wq^T|Wk^T|Wv^T
    unsigned short* wpt   = wqkvt + 3 * we;
    unsigned short* qkv   = wpt + we;         // [8192][3072] bf16
    unsigned short* ab    = qkv + (size_t)MROWS * QSTR;
    float*          bias3 = (float*)(ab + xe);

    cvt_x_kernel<<<(int)(xe / 8 / 256), 256, 0, stream>>>(x, xb);
    wt_kernel<<<dim3(32, 32, 4), 256, 0, stream>>>(
        Wq, Wk, Wv, Wp, wqkvt, wqkvt + we, wqkvt + 2 * we, wpt);
    pack_bias<<<12, 256, 0, stream>>>(bq, bk, bv, bias3);

    // fused QKV projection: 8-phase 256^2 pipeline, 32x12 = 384 blocks
    gemm_8ph<<<32 * 12, 512, 0, stream>>>(xb, wqkvt, bias3, qkv, QSTR, 1024);

    attn_mfma9<<<512, 256, 0, stream>>>(qkv, ab);

    // output projection -> fp32 (128^2 kernel: N=1024 shape, 512 blocks)
    gemm_glds<1><<<8 * 64, 256, 0, stream>>>(ab, wpt, bp, d_out,
                                             MROWS, CDIM, CDIM, 0);
}

// Round 13
// 169.149 us; speedup vs baseline: 1.2788x; 1.2788x over previous
//
#include <hip/hip_runtime.h>
#include <hip/hip_bf16.h>

#define CDIM   1024
#define NHEADS 16
#define DHEAD  64
#define BATCH  4
#define TSEQ   2048
#define MROWS  (BATCH * TSEQ)
#define QSTR   3072                /* fused qkv row stride */
#define NEG_BIG (-1e30f)
#define MASKVAL (-3.0e38f)
#define SCALE_L2E 0.18033688011f   /* 0.125 * log2(e) */
#define DEFER_TH 11.5416f          /* 8 nats in log2 units */

typedef __attribute__((ext_vector_type(8)))  short bf16x8;
typedef __attribute__((ext_vector_type(4)))  float f32x4;
typedef __attribute__((ext_vector_type(16))) float f32x16;

__device__ __forceinline__ unsigned short f2bf(float f) {
    __hip_bfloat16 h = __float2bfloat16(f);
    return *reinterpret_cast<unsigned short*>(&h);
}
__device__ __forceinline__ unsigned int cvtpk(float a, float b) {
    unsigned r;
    asm("v_cvt_pk_bf16_f32 %0, %1, %2" : "=v"(r) : "v"(a), "v"(b));
    return r;   // lo = bf16(a), hi = bf16(b)
}
__device__ __forceinline__ float ex2(float x) {   // raw v_exp_f32 (exp2)
    float r; asm("v_exp_f32 %0, %1" : "=v"(r) : "v"(x)); return r;
}

// ---------------- x: fp32 -> bf16 (8 elems/thread) --------------------------
__global__ __launch_bounds__(256)
void cvt_x_kernel(const float* __restrict__ in, unsigned short* __restrict__ out)
{
    size_t i = (size_t)blockIdx.x * 256 + threadIdx.x;
    const float4* p = reinterpret_cast<const float4*>(in) + i * 2;
    float4 a = p[0], b = p[1];
    uint4 o;
    o.x = (unsigned)f2bf(a.x) | ((unsigned)f2bf(a.y) << 16);
    o.y = (unsigned)f2bf(a.z) | ((unsigned)f2bf(a.w) << 16);
    o.z = (unsigned)f2bf(b.x) | ((unsigned)f2bf(b.y) << 16);
    o.w = (unsigned)f2bf(b.z) | ((unsigned)f2bf(b.w) << 16);
    *reinterpret_cast<uint4*>(out + i * 8) = o;
}

// ---------------- W[K][N] fp32 -> W^T[N][K] bf16 (32x32 LDS tiles) ----------
__global__ __launch_bounds__(256)
void wt_kernel(const float* __restrict__ W0, const float* __restrict__ W1,
               const float* __restrict__ W2, const float* __restrict__ W3,
               unsigned short* __restrict__ T0, unsigned short* __restrict__ T1,
               unsigned short* __restrict__ T2, unsigned short* __restrict__ T3)
{
    const float* W; unsigned short* T;
    switch (blockIdx.z) {
        case 0:  W = W0; T = T0; break;
        case 1:  W = W1; T = T1; break;
        case 2:  W = W2; T = T2; break;
        default: W = W3; T = T3; break;
    }
    __shared__ float tile[32][33];
    const int t = threadIdx.x;
    const int r = t >> 3;
    const int c4 = (t & 7) * 4;
    const int n0 = blockIdx.x * 32, k0 = blockIdx.y * 32;
    float4 v = *reinterpret_cast<const float4*>(&W[(size_t)(k0 + r) * CDIM + n0 + c4]);
    tile[r][c4 + 0] = v.x; tile[r][c4 + 1] = v.y;
    tile[r][c4 + 2] = v.z; tile[r][c4 + 3] = v.w;
    __syncthreads();
    uint2 o;
    o.x = (unsigned)f2bf(tile[c4 + 0][r]) | ((unsigned)f2bf(tile[c4 + 1][r]) << 16);
    o.y = (unsigned)f2bf(tile[c4 + 2][r]) | ((unsigned)f2bf(tile[c4 + 3][r]) << 16);
    *reinterpret_cast<uint2*>(&T[(size_t)(n0 + r) * CDIM + k0 + c4]) = o;
}

// ---------------- bias concat [bq|bk|bv] ------------------------------------
__global__ __launch_bounds__(256)
void pack_bias(const float* __restrict__ bq, const float* __restrict__ bk,
               const float* __restrict__ bv, float* __restrict__ o)
{
    int i = blockIdx.x * 256 + threadIdx.x;   // 0..3071
    float v = (i < 1024) ? bq[i] : (i < 2048 ? bk[i - 1024] : bv[i - 2048]);
    o[i] = v;
}

// ======== asymmetric-tile 8-phase GEMM: BMxBN in {128x256, 256x128} =========
// 512 thr = 8 waves (BM/64 x BN/64), per-wave 64x64 out (16 f32x4 acc).
// K=1024 = 16 K-tiles of 64, double-buffered; 2 compute phases per K-tile.
// Per pair-iteration (tiles e=2it in buf0, o=e+1 in buf1), stage halves:
//   p1: S(o), Llo(o) -> buf1 | p2: Lhi(o) -> buf1, then vmcnt(0)
//   p3: S(e+2) -> buf0       | p4: Llo/Lhi(e+2) -> buf0, then vmcnt(0)
// where S = smaller matrix region (1x 16KB half), L = larger (2 halves).
// WAR: no phase stages a region read in that same phase; reads complete at
// each phase's lgkmcnt(0) before any later-phase stage lands (>=1 barrier).
// RAW: vmcnt(0) every 2 phases; issue->wait gap ~2 phases covers HBM latency.
// glds: linear LDS dest; inverse-swizzled global source granule
// g=(tid&7)^((tid>>3)&7); reads swizzle slot (k*4+lg)^(lj&7) (rule 21 pair).
// Grid: QKV 64x12=768 (3 exact rounds of 256 CUs); P-proj 32x8=256 (1 round).

#define GBAR8  asm volatile("s_barrier" ::: "memory")
#define LGKM0  asm volatile("s_waitcnt lgkmcnt(0)" ::: "memory")
#define VMC0   asm volatile("s_waitcnt vmcnt(0)" ::: "memory")

#define STAGE8(bufp, off, srcp) do { \
    __builtin_amdgcn_global_load_lds( \
        (const __attribute__((address_space(1))) void*)(srcp), \
        (__attribute__((address_space(3))) void*)((bufp) + (off) + wv * 1024), 16, 0, 0); \
    __builtin_amdgcn_global_load_lds( \
        (const __attribute__((address_space(1))) void*)((srcp) + 65536), \
        (__attribute__((address_space(3))) void*)((bufp) + (off) + 8192 + wv * 1024), 16, 0, 0); \
} while (0)

#define LDA_ALL(Ab) do { \
    _Pragma("unroll") for (int m_ = 0; m_ < 4; ++m_) { \
        const int rl_ = wr * 64 + m_ * 16 + lj; \
        _Pragma("unroll") for (int k_ = 0; k_ < 2; ++k_) \
            af[m_][k_] = *reinterpret_cast<const bf16x8*>( \
                (Ab) + rl_ * 128 + (((k_ * 4 + lg) ^ (lj & 7)) * 16)); \
    } } while (0)

#define LDB_PAIR(Bb, pairi) do { \
    _Pragma("unroll") for (int n_ = 0; n_ < 2; ++n_) { \
        const int rl_ = wc * 64 + ((pairi) * 2 + n_) * 16 + lj; \
        _Pragma("unroll") for (int k_ = 0; k_ < 2; ++k_) \
            bfr[n_][k_] = *reinterpret_cast<const bf16x8*>( \
                (Bb) + rl_ * 128 + (((k_ * 4 + lg) ^ (lj & 7)) * 16)); \
    } } while (0)

#define MM_PAIR(npair) do { \
    __builtin_amdgcn_s_setprio(1); \
    _Pragma("unroll") for (int m_ = 0; m_ < 4; ++m_) \
        _Pragma("unroll") for (int n_ = 0; n_ < 2; ++n_) \
            _Pragma("unroll") for (int k_ = 0; k_ < 2; ++k_) \
                acc[m_][(npair) * 2 + n_] = \
                    __builtin_amdgcn_mfma_f32_16x16x32_bf16( \
                        af[m_][k_], bfr[n_][k_], acc[m_][(npair) * 2 + n_], 0, 0, 0); \
    __builtin_amdgcn_s_setprio(0); \
} while (0)

template<int BM, int BN, int OUTMODE>
__global__ __launch_bounds__(512)
void gemm_8ph2(const unsigned short* __restrict__ A,
               const unsigned short* __restrict__ BT,
               const float* __restrict__ bias,
               void* __restrict__ Cout, int N, int nScaled)
{
    constexpr int WN = BN / 64;                 // waves along N
    constexpr bool A_SMALL = (BM == 128);       // which matrix is the 1-half side
    constexpr int AOFF = 0;
    constexpr int BOFF = BM * 128;              // B region byte offset in buffer
    constexpr int SOFF   = A_SMALL ? AOFF : BOFF;
    constexpr int LLOOFF = A_SMALL ? BOFF : AOFF;
    constexpr int LHIOFF = LLOOFF + 16384;

    __shared__ __align__(16) char lds8[2][(BM + BN) * 128];
    const int tid = threadIdx.x;
    const int nbn = N / BN;
    const int bid = blockIdx.x;
    const int wg  = (bid & 7) * ((int)gridDim.x >> 3) + (bid >> 3);  // XCD swizzle
    const int n0  = (wg % nbn) * BN;
    const int m0  = (wg / nbn) * BM;

    const int lane = tid & 63, wv = tid >> 6;
    const int wr = wv / WN, wc = wv % WN;
    const int lj = lane & 15, lg = lane >> 4;
    const int srow = tid >> 3;                              // 0..63
    const int gsw  = 8 * ((tid & 7) ^ ((tid >> 3) & 7));    // src granule (elems)

    char* buf0 = &lds8[0][0];
    char* buf1 = &lds8[1][0];

    // stage source pointers (row stride K=1024)
    const unsigned short* Sm  = A_SMALL ? A : BT;
    const int             sb  = A_SMALL ? m0 : n0;
    const unsigned short* Lm  = A_SMALL ? BT : A;
    const int             lb  = A_SMALL ? n0 : m0;
    const unsigned short* Ss  = Sm + (size_t)(sb + srow) * 1024 + gsw;
    const unsigned short* Llo = Lm + (size_t)(lb + srow) * 1024 + gsw;
    const unsigned short* Lhi = Lm + (size_t)(lb + 128 + srow) * 1024 + gsw;

    f32x4 acc[4][4];
    #pragma unroll
    for (int i = 0; i < 4; ++i)
        #pragma unroll
        for (int j = 0; j < 4; ++j) acc[i][j] = f32x4{0.f, 0.f, 0.f, 0.f};

    // prologue: tile 0 -> buf0
    STAGE8(buf0, SOFF,   Ss);
    STAGE8(buf0, LLOOFF, Llo);
    STAGE8(buf0, LHIOFF, Lhi);
    VMC0; GBAR8;

    bf16x8 af[4][2], bfr[2][2];

    for (int it = 0; it < 8; ++it) {
        const int e = 2 * it, o = e + 1;
        const bool se = (e + 2) < 16;

        // ===== K-tile e (buf0) =====
        {
            char* Ab = buf0 + AOFF;
            char* Bb = buf0 + BOFF;
            // p1: A all-m + B n0-1 | stage S(o), Llo(o) -> buf1
            LDA_ALL(Ab); LDB_PAIR(Bb, 0);
            STAGE8(buf1, SOFF,   Ss  + o * 64);
            STAGE8(buf1, LLOOFF, Llo + o * 64);
            GBAR8; LGKM0; MM_PAIR(0); GBAR8;
            // p2: B n2-3 | stage Lhi(o) -> buf1 ; drain before p3 consumes
            LDB_PAIR(Bb, 1);
            STAGE8(buf1, LHIOFF, Lhi + o * 64);
            GBAR8; LGKM0; MM_PAIR(1);
            VMC0; GBAR8;
        }
        // ===== K-tile o (buf1) =====
        {
            char* Ab = buf1 + AOFF;
            char* Bb = buf1 + BOFF;
            // p3: A all-m + B n0-1 | stage S(e+2) -> buf0
            LDA_ALL(Ab); LDB_PAIR(Bb, 0);
            if (se) STAGE8(buf0, SOFF, Ss + (e + 2) * 64);
            GBAR8; LGKM0; MM_PAIR(0); GBAR8;
            // p4: B n2-3 | stage Llo/Lhi(e+2) -> buf0 ; drain before next p1
            LDB_PAIR(Bb, 1);
            if (se) {
                STAGE8(buf0, LLOOFF, Llo + (e + 2) * 64);
                STAGE8(buf0, LHIOFF, Lhi + (e + 2) * 64);
            }
            GBAR8; LGKM0; MM_PAIR(1);
            VMC0; GBAR8;
        }
    }

    // epilogue: bias (+ optional softmax-scale fold), store
    const float sc = (OUTMODE == 0 && n0 < nScaled) ? SCALE_L2E : 1.0f;
    float bcol[4];
    #pragma unroll
    for (int nr = 0; nr < 4; ++nr) bcol[nr] = bias[n0 + wc * 64 + nr * 16 + lj];

    #pragma unroll
    for (int mr = 0; mr < 4; ++mr) {
        #pragma unroll
        for (int r4 = 0; r4 < 4; ++r4) {
            const int row = m0 + wr * 64 + mr * 16 + lg * 4 + r4;
            #pragma unroll
            for (int nr = 0; nr < 4; ++nr) {
                const int col = n0 + wc * 64 + nr * 16 + lj;
                float v = (acc[mr][nr][r4] + bcol[nr]) * sc;
                if (OUTMODE == 0)
                    reinterpret_cast<unsigned short*>(Cout)[(size_t)row * N + col] = f2bf(v);
                else
                    reinterpret_cast<float*>(Cout)[(size_t)row * N + col] = v;
            }
        }
    }
}

// ---------------- MFMA flash attention (R7/R9-verified: 79us, VGPR 124) -----
// 512 blocks, 4 waves x 32 q-rows = 128-row q-tile; balanced pair (p, 15-p)
// sequentially (uniform 34 KV-iterations). XCD-grouped id mapping (R5).
// KV single-LDS-buffer, reg prefetch of kt+1. cvt_pk P-pack, tree reductions,
// raw v_exp, v_perm V-pack. DO NOT: __launch_bounds__ min-waves (R8 spill),
// KVBLK=128 (R12 live-range spill), 1024-block remap (R11 dispatch), T15 (R6).
#define PV_STEP(m, T, rb) { \
    unsigned int w01 = cvtpk(T[(rb)+0], T[(rb)+1]); \
    unsigned int w23 = cvtpk(T[(rb)+2], T[(rb)+3]); \
    unsigned int w45 = cvtpk(T[(rb)+4], T[(rb)+5]); \
    unsigned int w67 = cvtpk(T[(rb)+6], T[(rb)+7]); \
    asm("v_permlane32_swap_b32 %0, %1" : "+v"(w01), "+v"(w45)); \
    asm("v_permlane32_swap_b32 %0, %1" : "+v"(w23), "+v"(w67)); \
    union { unsigned int u[4]; bf16x8 v; } pa; \
    pa.u[0] = w01; pa.u[1] = w23; pa.u[2] = w45; pa.u[3] = w67; \
    const int voff = (32 * (m) + 16 * hi) ^ lqswz; \
    bf16x8 va = *reinterpret_cast<const bf16x8*>(VTB + lq * 128 + voff); \
    bf16x8 vb = *reinterpret_cast<const bf16x8*>(VTB + (lq + 32) * 128 + voff); \
    y0 = __builtin_amdgcn_mfma_f32_32x32x16_bf16(va, pa.v, y0, 0, 0, 0); \
    y1 = __builtin_amdgcn_mfma_f32_32x32x16_bf16(vb, pa.v, y1, 0, 0, 0); \
}

__global__ __launch_bounds__(256)
void attn_mfma6(const unsigned short* __restrict__ QKV, unsigned short* __restrict__ Yb)
{
    __shared__ unsigned short Ks[64 * 64];    // [key][d], swizzled
    __shared__ unsigned short VTs[64 * 64];   // [d][key], swizzled
    __shared__ unsigned short Ysc[4][32 * 72];// per-wave [q][d], 144B stride

    const int tid = threadIdx.x, lane = tid & 63, wid = tid >> 6;
    const int lq = lane & 31, hi = lane >> 5;
    const int lqswz = (lq & 7) << 4;

    // XCD-grouped decomposition: id%8 == hb%8 -> same (h,b) shares an XCD
    const int id  = blockIdx.x;
    const int kk  = id >> 3;
    const int hb  = (id & 7) + 8 * (kk >> 3);
    const int pair = kk & 7;
    const int h = hb & 15, bz = hb >> 4;

    const size_t rowbase = (size_t)bz * TSEQ;
    const int hq = h * DHEAD, hk = 1024 + h * DHEAD, hv = 2048 + h * DHEAD;
    char* KsB = (char*)Ks;
    char* VTB = (char*)VTs;

    // staging thread mapping (constant per thread)
    const int krow = tid >> 3;           // K rows krow, krow+32
    const int kswz = ((tid & 7) * 16) ^ ((krow & 7) << 4);
    const int vk2  = 2 * (tid & 31);     // V key-pair
    const int vdg  = (tid >> 5) * 8;     // V d-group
    const int vkb  = vk2 * 2;            // byte offset of pair

    for (int iter = 0; iter < 2; ++iter) {
        const int qtile = iter ? (15 - pair) : pair;
        const int q0 = qtile * 128;
        const int wq = q0 + wid * 32;

        bf16x8 qf[4];                            // Q^T B-frags: d = 16s + 8hi + j
        {
            const unsigned short* qp = QKV + (rowbase + wq + lq) * QSTR + hq + hi * 8;
            #pragma unroll
            for (int s = 0; s < 4; ++s)
                qf[s] = *reinterpret_cast<const bf16x8*>(qp + s * 16);
        }
        f32x16 y0, y1;                           // Y^T tiles: d 0..31 / 32..63
        #pragma unroll
        for (int r = 0; r < 16; ++r) { y0[r] = 0.f; y1[r] = 0.f; }
        float mrow = NEG_BIG, lrow = 0.f;

        const int ktend = 2 * qtile + 2;

        // prefetch tile 0 into registers
        uint4 kr0, kr1, vr0, vr1;
        {
            const unsigned short* kp = QKV + (rowbase + krow) * QSTR + hk + (tid & 7) * 8;
            kr0 = *reinterpret_cast<const uint4*>(kp);
            kr1 = *reinterpret_cast<const uint4*>(kp + 32 * QSTR);
            const unsigned short* vp = QKV + (rowbase + vk2) * QSTR + hv + vdg;
            vr0 = *reinterpret_cast<const uint4*>(vp);
            vr1 = *reinterpret_cast<const uint4*>(vp + QSTR);
        }

        for (int kt = 0; kt < ktend; ++kt) {
            __syncthreads();                     // previous tile's consumers done
            // ---- write prefetched regs -> LDS (K swizzled, V^T perm-packed)
            *reinterpret_cast<uint4*>(KsB + krow * 128 + kswz) = kr0;
            *reinterpret_cast<uint4*>(KsB + (krow + 32) * 128 + kswz) = kr1;
            {
                unsigned pe, po;
                pe = __builtin_amdgcn_perm(vr1.x, vr0.x, 0x05040100u);
                po = __builtin_amdgcn_perm(vr1.x, vr0.x, 0x07060302u);
                *reinterpret_cast<unsigned*>(VTB + (vdg + 0) * 128 + (vkb ^ 0x00)) = pe;
                *reinterpret_cast<unsigned*>(VTB + (vdg + 1) * 128 + (vkb ^ 0x10)) = po;
                pe = __builtin_amdgcn_perm(vr1.y, vr0.y, 0x05040100u);
                po = __builtin_amdgcn_perm(vr1.y, vr0.y, 0x07060302u);
                *reinterpret_cast<unsigned*>(VTB + (vdg + 2) * 128 + (vkb ^ 0x20)) = pe;
                *reinterpret_cast<unsigned*>(VTB + (vdg + 3) * 128 + (vkb ^ 0x30)) = po;
                pe = __builtin_amdgcn_perm(vr1.z, vr0.z, 0x05040100u);
                po = __builtin_amdgcn_perm(vr1.z, vr0.z, 0x07060302u);
                *reinterpret_cast<unsigned*>(VTB + (vdg + 4) * 128 + (vkb ^ 0x40)) = pe;
                *reinterpret_cast<unsigned*>(VTB + (vdg + 5) * 128 + (vkb ^ 0x50)) = po;
                pe = __builtin_amdgcn_perm(vr1.w, vr0.w, 0x05040100u);
                po = __builtin_amdgcn_perm(vr1.w, vr0.w, 0x07060302u);
                *reinterpret_cast<unsigned*>(VTB + (vdg + 6) * 128 + (vkb ^ 0x60)) = pe;
                *reinterpret_cast<unsigned*>(VTB + (vdg + 7) * 128 + (vkb ^ 0x70)) = po;
            }
            __syncthreads();                     // LDS tile ready

            // ---- issue next tile's global loads (latency hides under compute)
            if (kt + 1 < ktend) {
                const unsigned short* kp = QKV + (rowbase + (kt + 1) * 64 + krow) * QSTR + hk + (tid & 7) * 8;
                kr0 = *reinterpret_cast<const uint4*>(kp);
                kr1 = *reinterpret_cast<const uint4*>(kp + 32 * QSTR);
                const unsigned short* vp = QKV + (rowbase + (kt + 1) * 64 + vk2) * QSTR + hv + vdg;
                vr0 = *reinterpret_cast<const uint4*>(vp);
                vr1 = *reinterpret_cast<const uint4*>(vp + QSTR);
            }

            if (kt * 64 > wq + 31) continue;     // tile above diagonal for this wave

            // ---- S^T = K Q^T (8 mfma 32x32x16); scale pre-folded into Q
            f32x16 s0, s1;
            #pragma unroll
            for (int r = 0; r < 16; ++r) { s0[r] = 0.f; s1[r] = 0.f; }
            #pragma unroll
            for (int s = 0; s < 4; ++s) {
                const int off = (s * 32 + hi * 16) ^ lqswz;
                bf16x8 k0 = *reinterpret_cast<const bf16x8*>(KsB + lq * 128 + off);
                bf16x8 k1 = *reinterpret_cast<const bf16x8*>(KsB + (lq + 32) * 128 + off);
                s0 = __builtin_amdgcn_mfma_f32_32x32x16_bf16(k0, qf[s], s0, 0, 0, 0);
                s1 = __builtin_amdgcn_mfma_f32_32x32x16_bf16(k1, qf[s], s1, 0, 0, 0);
            }

            // ---- causal mask (diagonal tiles only)
            const bool diag = (kt * 64 + 63) > wq;
            if (diag) {
                const int q_own = wq + lq;
                #pragma unroll
                for (int r = 0; r < 16; ++r) {
                    const int kl = kt * 64 + (r & 3) + 8 * (r >> 2) + 4 * hi;
                    if (kl > q_own) s0[r] = MASKVAL;
                    if (kl + 32 > q_own) s1[r] = MASKVAL;
                }
            }

            // ---- tree row max + pair exchange
            float t8[8];
            #pragma unroll
            for (int r = 0; r < 8; ++r)
                t8[r] = fmaxf(fmaxf(s0[r], s0[r + 8]), fmaxf(s1[r], s1[r + 8]));
            #pragma unroll
            for (int r = 0; r < 4; ++r) t8[r] = fmaxf(t8[r], t8[r + 4]);
            float pm = fmaxf(fmaxf(t8[0], t8[1]), fmaxf(t8[2], t8[3]));
            pm = fmaxf(pm, __shfl_xor(pm, 32));

            // ---- defer-max rescale (T13)
            if (__any(pm > mrow + DEFER_TH)) {
                const float mnew = fmaxf(mrow, pm);
                const float alpha = ex2(mrow - mnew);
                #pragma unroll
                for (int r = 0; r < 16; ++r) { y0[r] *= alpha; y1[r] *= alpha; }
                lrow *= alpha;
                mrow = mnew;
            }
            // ---- exp2 + tree row sum
            #pragma unroll
            for (int r = 0; r < 16; ++r) {
                s0[r] = ex2(s0[r] - mrow);
                s1[r] = ex2(s1[r] - mrow);
            }
            float a8[8];
            #pragma unroll
            for (int r = 0; r < 8; ++r) a8[r] = (s0[r] + s0[r + 8]) + (s1[r] + s1[r + 8]);
            #pragma unroll
            for (int r = 0; r < 4; ++r) a8[r] += a8[r + 4];
            float sum = (a8[0] + a8[1]) + (a8[2] + a8[3]);
            sum += __shfl_xor(sum, 32);
            lrow += sum;

            // ---- Y^T += V^T P^T (8 mfma); P^T frags via cvt_pk+permlane32_swap
            PV_STEP(0, s0, 0)
            PV_STEP(1, s0, 8)
            PV_STEP(2, s1, 0)
            PV_STEP(3, s1, 8)
        }

        // ---- epilogue: normalize, transpose via per-wave LDS, coalesced store
        {
            const float inv = 1.f / lrow;
            char* ysb = (char*)&Ysc[wid][0];
            #pragma unroll
            for (int t = 0; t < 8; ++t) {
                const int dl = ((2 * t) & 3) + 8 * (t >> 1) + 4 * hi;
                unsigned int wa = cvtpk(y0[2 * t] * inv, y0[2 * t + 1] * inv);
                unsigned int wb = cvtpk(y1[2 * t] * inv, y1[2 * t + 1] * inv);
                *reinterpret_cast<unsigned int*>(ysb + lq * 144 + dl * 2) = wa;
                *reinterpret_cast<unsigned int*>(ysb + lq * 144 + (dl + 32) * 2) = wb;
            }
            #pragma unroll
            for (int u = 0; u < 4; ++u) {
                const int rr = lane >> 1, ch = (lane & 1) + 2 * u;
                uint4 val = *reinterpret_cast<const uint4*>(ysb + rr * 144 + ch * 16);
                *reinterpret_cast<uint4*>(Yb + (rowbase + q0 + wid * 32 + rr) * CDIM + h * DHEAD + ch * 8) = val;
            }
        }
    }
}

// ---------------------------------------------------------------------------
extern "C" void kernel_launch(void* const* d_in, const int* in_sizes, int n_in,
                              void* d_out, int out_size, void* d_ws, size_t ws_size,
                              hipStream_t stream)
{
    const float* x  = (const float*)d_in[0];
    const float* Wk = (const float*)d_in[1];
    const float* bk = (const float*)d_in[2];
    const float* Wq = (const float*)d_in[3];
    const float* bq = (const float*)d_in[4];
    const float* Wv = (const float*)d_in[5];
    const float* bv = (const float*)d_in[6];
    const float* Wp = (const float*)d_in[7];
    const float* bp = (const float*)d_in[8];

    const size_t xe = (size_t)MROWS * CDIM;   // 8,388,608
    const size_t we = (size_t)CDIM * CDIM;    // 1,048,576
    unsigned short* xb    = (unsigned short*)d_ws;
    unsigned short* wqkvt = xb + xe;          // [3072][1024] = Wq^T|Wk^T|Wv^T
    unsigned short* wpt   = wqkvt + 3 * we;
    unsigned short* qkv   = wpt + we;         // [8192][3072] bf16
    unsigned short* ab    = qkv + (size_t)MROWS * QSTR;
    float*          bias3 = (float*)(ab + xe);

    cvt_x_kernel<<<(int)(xe / 8 / 256), 256, 0, stream>>>(x, xb);
    wt_kernel<<<dim3(32, 32, 4), 256, 0, stream>>>(
        Wq, Wk, Wv, Wp, wqkvt, wqkvt + we, wqkvt + 2 * we, wpt);
    pack_bias<<<12, 256, 0, stream>>>(bq, bk, bv, bias3);

    // fused QKV projection: 128x256-tile 8-phase, 64x12 = 768 blocks (3 rounds)
    gemm_8ph2<128, 256, 0><<<768, 512, 0, stream>>>(xb, wqkvt, bias3, qkv,
                                                    QSTR, 1024);

    attn_mfma6<<<512, 256, 0, stream>>>(qkv, ab);

    // output projection -> fp32: 256x128-tile 8-phase, 32x8 = 256 blocks (1 round)
    gemm_8ph2<256, 128, 1><<<256, 512, 0, stream>>>(ab, wpt, bp, d_out,
                                                    CDIM, 0);
}

// Round 14
// 166.712 us; speedup vs baseline: 1.2975x; 1.0146x over previous
//
#include <hip/hip_runtime.h>
#include <hip/hip_bf16.h>

#define CDIM   1024
#define NHEADS 16
#define DHEAD  64
#define BATCH  4
#define TSEQ   2048
#define MROWS  (BATCH * TSEQ)
#define QSTR   3072                /* fused qkv row stride */
#define NEG_BIG (-1e30f)
#define MASKVAL (-3.0e38f)
#define SCALE_L2E 0.18033688011f   /* 0.125 * log2(e) */
#define DEFER_TH 11.5416f          /* 8 nats in log2 units */

typedef __attribute__((ext_vector_type(8)))  short bf16x8;
typedef __attribute__((ext_vector_type(4)))  float f32x4;
typedef __attribute__((ext_vector_type(16))) float f32x16;

__device__ __forceinline__ unsigned short f2bf(float f) {
    __hip_bfloat16 h = __float2bfloat16(f);
    return *reinterpret_cast<unsigned short*>(&h);
}
__device__ __forceinline__ unsigned int cvtpk(float a, float b) {
    unsigned r;
    asm("v_cvt_pk_bf16_f32 %0, %1, %2" : "=v"(r) : "v"(a), "v"(b));
    return r;   // lo = bf16(a), hi = bf16(b)
}
__device__ __forceinline__ float ex2(float x) {   // raw v_exp_f32 (exp2)
    float r; asm("v_exp_f32 %0, %1" : "=v"(r) : "v"(x)); return r;
}

// ---------------- x: fp32 -> bf16 (8 elems/thread) --------------------------
__global__ __launch_bounds__(256)
void cvt_x_kernel(const float* __restrict__ in, unsigned short* __restrict__ out)
{
    size_t i = (size_t)blockIdx.x * 256 + threadIdx.x;
    const float4* p = reinterpret_cast<const float4*>(in) + i * 2;
    float4 a = p[0], b = p[1];
    uint4 o;
    o.x = (unsigned)f2bf(a.x) | ((unsigned)f2bf(a.y) << 16);
    o.y = (unsigned)f2bf(a.z) | ((unsigned)f2bf(a.w) << 16);
    o.z = (unsigned)f2bf(b.x) | ((unsigned)f2bf(b.y) << 16);
    o.w = (unsigned)f2bf(b.z) | ((unsigned)f2bf(b.w) << 16);
    *reinterpret_cast<uint4*>(out + i * 8) = o;
}

// ---------------- W[K][N] fp32 -> W^T[N][K] bf16 (32x32 LDS tiles) ----------
__global__ __launch_bounds__(256)
void wt_kernel(const float* __restrict__ W0, const float* __restrict__ W1,
               const float* __restrict__ W2, const float* __restrict__ W3,
               unsigned short* __restrict__ T0, unsigned short* __restrict__ T1,
               unsigned short* __restrict__ T2, unsigned short* __restrict__ T3)
{
    const float* W; unsigned short* T;
    switch (blockIdx.z) {
        case 0:  W = W0; T = T0; break;
        case 1:  W = W1; T = T1; break;
        case 2:  W = W2; T = T2; break;
        default: W = W3; T = T3; break;
    }
    __shared__ float tile[32][33];
    const int t = threadIdx.x;
    const int r = t >> 3;
    const int c4 = (t & 7) * 4;
    const int n0 = blockIdx.x * 32, k0 = blockIdx.y * 32;
    float4 v = *reinterpret_cast<const float4*>(&W[(size_t)(k0 + r) * CDIM + n0 + c4]);
    tile[r][c4 + 0] = v.x; tile[r][c4 + 1] = v.y;
    tile[r][c4 + 2] = v.z; tile[r][c4 + 3] = v.w;
    __syncthreads();
    uint2 o;
    o.x = (unsigned)f2bf(tile[c4 + 0][r]) | ((unsigned)f2bf(tile[c4 + 1][r]) << 16);
    o.y = (unsigned)f2bf(tile[c4 + 2][r]) | ((unsigned)f2bf(tile[c4 + 3][r]) << 16);
    *reinterpret_cast<uint2*>(&T[(size_t)(n0 + r) * CDIM + k0 + c4]) = o;
}

// ---------------- bias concat [bq|bk|bv] ------------------------------------
__global__ __launch_bounds__(256)
void pack_bias(const float* __restrict__ bq, const float* __restrict__ bk,
               const float* __restrict__ bv, float* __restrict__ o)
{
    int i = blockIdx.x * 256 + threadIdx.x;   // 0..3071
    float v = (i < 1024) ? bq[i] : (i < 2048 ? bk[i - 1024] : bv[i - 2048]);
    o[i] = v;
}

// ======== 3-buffer counted-vmcnt pipelined GEMM (T3+T4, asym tiles) =========
// BMxBN in {128x256, 256x128}, 512 thr = 8 waves, per-wave 64x64 out.
// K=1024 = 16 K-tiles of 64. THREE rotating LDS buffers (3 x 48KB = 144KB);
// during tile t's 2 phases, ALL 6 halves of tile t+2 are staged into
// buf[(t+2)%3] -> stage-to-read distance = 2 K-tiles, enabling the COUNTED
// wait (m218: counted-vs-drain0 = +38..73%; R13's drain-0 variant was the
// neutral "8-phase==1-phase" case). Steady state at end of tile t:
// outstanding = 6 loads (t+1, issued during t-1) + 6 (t+2, issued during t)
// -> vmcnt(6) drains exactly t+1's, leaves t+2's in flight across the
// barrier. Never 0 in main loop; tail (no t+2 stage) uses vmcnt(0).
// WAR: stages into buf[(t+2)%3]=buf[(t-1)%3] are issued after the barrier
// that closed tile t-1's reads. RAW: the per-phase lgkmcnt(0) covers ds_read.
// glds: linear LDS dest; inverse-swizzled global source granule
// g=(tid&7)^((tid>>3)&7); reads swizzle slot (k*4+lg)^(lj&7) (rule 21 pair).
// Grid: QKV 64x12=768 (3 exact CU rounds); P-proj 32x8=256 (1 exact round).

#define GBAR8  asm volatile("s_barrier" ::: "memory")
#define LGKM0  asm volatile("s_waitcnt lgkmcnt(0)" ::: "memory")
#define VMC6   asm volatile("s_waitcnt vmcnt(6)" ::: "memory")
#define VMC0   asm volatile("s_waitcnt vmcnt(0)" ::: "memory")

#define STAGE8(bufp, off, srcp) do { \
    __builtin_amdgcn_global_load_lds( \
        (const __attribute__((address_space(1))) void*)(srcp), \
        (__attribute__((address_space(3))) void*)((bufp) + (off) + wv * 1024), 16, 0, 0); \
    __builtin_amdgcn_global_load_lds( \
        (const __attribute__((address_space(1))) void*)((srcp) + 65536), \
        (__attribute__((address_space(3))) void*)((bufp) + (off) + 8192 + wv * 1024), 16, 0, 0); \
} while (0)

#define LDA_ALL(Ab) do { \
    _Pragma("unroll") for (int m_ = 0; m_ < 4; ++m_) { \
        const int rl_ = wr * 64 + m_ * 16 + lj; \
        _Pragma("unroll") for (int k_ = 0; k_ < 2; ++k_) \
            af[m_][k_] = *reinterpret_cast<const bf16x8*>( \
                (Ab) + rl_ * 128 + (((k_ * 4 + lg) ^ (lj & 7)) * 16)); \
    } } while (0)

#define LDB_PAIR(Bb, pairi) do { \
    _Pragma("unroll") for (int n_ = 0; n_ < 2; ++n_) { \
        const int rl_ = wc * 64 + ((pairi) * 2 + n_) * 16 + lj; \
        _Pragma("unroll") for (int k_ = 0; k_ < 2; ++k_) \
            bfr[n_][k_] = *reinterpret_cast<const bf16x8*>( \
                (Bb) + rl_ * 128 + (((k_ * 4 + lg) ^ (lj & 7)) * 16)); \
    } } while (0)

#define MM_PAIR(npair) do { \
    __builtin_amdgcn_s_setprio(1); \
    _Pragma("unroll") for (int m_ = 0; m_ < 4; ++m_) \
        _Pragma("unroll") for (int n_ = 0; n_ < 2; ++n_) \
            _Pragma("unroll") for (int k_ = 0; k_ < 2; ++k_) \
                acc[m_][(npair) * 2 + n_] = \
                    __builtin_amdgcn_mfma_f32_16x16x32_bf16( \
                        af[m_][k_], bfr[n_][k_], acc[m_][(npair) * 2 + n_], 0, 0, 0); \
    __builtin_amdgcn_s_setprio(0); \
} while (0)

template<int BM, int BN, int OUTMODE>
__global__ __launch_bounds__(512)
void gemm_8ph3(const unsigned short* __restrict__ A,
               const unsigned short* __restrict__ BT,
               const float* __restrict__ bias,
               void* __restrict__ Cout, int N, int nScaled)
{
    constexpr int WN = BN / 64;                 // waves along N
    constexpr bool A_SMALL = (BM == 128);       // which matrix is the 1-half side
    constexpr int AOFF = 0;
    constexpr int BOFF = BM * 128;              // B region byte offset in buffer
    constexpr int SOFF   = A_SMALL ? AOFF : BOFF;
    constexpr int LLOOFF = A_SMALL ? BOFF : AOFF;
    constexpr int LHIOFF = LLOOFF + 16384;
    constexpr int BUFSZ  = (BM + BN) * 128;     // 49152 bytes

    __shared__ __align__(16) char lds8[3 * BUFSZ];   // 144 KB
    const int tid = threadIdx.x;
    const int nbn = N / BN;
    const int bid = blockIdx.x;
    const int wg  = (bid & 7) * ((int)gridDim.x >> 3) + (bid >> 3);  // XCD swizzle
    const int n0  = (wg % nbn) * BN;
    const int m0  = (wg / nbn) * BM;

    const int lane = tid & 63, wv = tid >> 6;
    const int wr = wv / WN, wc = wv % WN;
    const int lj = lane & 15, lg = lane >> 4;
    const int srow = tid >> 3;                              // 0..63
    const int gsw  = 8 * ((tid & 7) ^ ((tid >> 3) & 7));    // src granule (elems)

    // stage source pointers (row stride K=1024)
    const unsigned short* Sm  = A_SMALL ? A : BT;
    const int             sb  = A_SMALL ? m0 : n0;
    const unsigned short* Lm  = A_SMALL ? BT : A;
    const int             lb  = A_SMALL ? n0 : m0;
    const unsigned short* Ss  = Sm + (size_t)(sb + srow) * 1024 + gsw;
    const unsigned short* Llo = Lm + (size_t)(lb + srow) * 1024 + gsw;
    const unsigned short* Lhi = Lm + (size_t)(lb + 128 + srow) * 1024 + gsw;

    f32x4 acc[4][4];
    #pragma unroll
    for (int i = 0; i < 4; ++i)
        #pragma unroll
        for (int j = 0; j < 4; ++j) acc[i][j] = f32x4{0.f, 0.f, 0.f, 0.f};

    char* bufA = &lds8[0];              // tile t
    char* bufB = &lds8[BUFSZ];          // tile t+1
    char* bufC = &lds8[2 * BUFSZ];      // tile t+2 (being staged)

    // prologue: stage tiles 0 and 1; wait for tile 0's 6 (leave tile 1's 6)
    STAGE8(bufA, SOFF,   Ss);
    STAGE8(bufA, LLOOFF, Llo);
    STAGE8(bufA, LHIOFF, Lhi);
    STAGE8(bufB, SOFF,   Ss  + 64);
    STAGE8(bufB, LLOOFF, Llo + 64);
    STAGE8(bufB, LHIOFF, Lhi + 64);
    VMC6; GBAR8;

    bf16x8 af[4][2], bfr[2][2];

    for (int t = 0; t < 16; ++t) {
        const bool st = (t + 2) < 16;
        const int  t2 = (t + 2) * 64;

        // phase A: A all-m + B n0-1 | stage S(t+2), Llo(t+2) -> bufC
        LDA_ALL(bufA + AOFF); LDB_PAIR(bufA + BOFF, 0);
        if (st) {
            STAGE8(bufC, SOFF,   Ss  + t2);
            STAGE8(bufC, LLOOFF, Llo + t2);
        }
        GBAR8; LGKM0; MM_PAIR(0); GBAR8;

        // phase B: B n2-3 | stage Lhi(t+2) -> bufC | counted wait
        LDB_PAIR(bufA + BOFF, 1);
        if (st) STAGE8(bufC, LHIOFF, Lhi + t2);
        GBAR8; LGKM0; MM_PAIR(1);
        if (st) { VMC6; } else { VMC0; }
        GBAR8;

        // rotate buffers
        char* tmp = bufA; bufA = bufB; bufB = bufC; bufC = tmp;
    }

    // epilogue: bias (+ optional softmax-scale fold), store
    const float sc = (OUTMODE == 0 && n0 < nScaled) ? SCALE_L2E : 1.0f;
    float bcol[4];
    #pragma unroll
    for (int nr = 0; nr < 4; ++nr) bcol[nr] = bias[n0 + wc * 64 + nr * 16 + lj];

    #pragma unroll
    for (int mr = 0; mr < 4; ++mr) {
        #pragma unroll
        for (int r4 = 0; r4 < 4; ++r4) {
            const int row = m0 + wr * 64 + mr * 16 + lg * 4 + r4;
            #pragma unroll
            for (int nr = 0; nr < 4; ++nr) {
                const int col = n0 + wc * 64 + nr * 16 + lj;
                float v = (acc[mr][nr][r4] + bcol[nr]) * sc;
                if (OUTMODE == 0)
                    reinterpret_cast<unsigned short*>(Cout)[(size_t)row * N + col] = f2bf(v);
                else
                    reinterpret_cast<float*>(Cout)[(size_t)row * N + col] = v;
            }
        }
    }
}

// ---------------- MFMA flash attention (R7/R9-verified: 79us, VGPR 124) -----
// 512 blocks, 4 waves x 32 q-rows = 128-row q-tile; balanced pair (p, 15-p)
// sequentially (uniform 34 KV-iterations). XCD-grouped id mapping (R5).
// KV single-LDS-buffer, reg prefetch of kt+1. cvt_pk P-pack, tree reductions,
// raw v_exp, v_perm V-pack. DO NOT: __launch_bounds__ min-waves (R8 spill),
// KVBLK=128 (R12 live-range spill), 1024-block remap (R11 dispatch), T15 (R6).
#define PV_STEP(m, T, rb) { \
    unsigned int w01 = cvtpk(T[(rb)+0], T[(rb)+1]); \
    unsigned int w23 = cvtpk(T[(rb)+2], T[(rb)+3]); \
    unsigned int w45 = cvtpk(T[(rb)+4], T[(rb)+5]); \
    unsigned int w67 = cvtpk(T[(rb)+6], T[(rb)+7]); \
    asm("v_permlane32_swap_b32 %0, %1" : "+v"(w01), "+v"(w45)); \
    asm("v_permlane32_swap_b32 %0, %1" : "+v"(w23), "+v"(w67)); \
    union { unsigned int u[4]; bf16x8 v; } pa; \
    pa.u[0] = w01; pa.u[1] = w23; pa.u[2] = w45; pa.u[3] = w67; \
    const int voff = (32 * (m) + 16 * hi) ^ lqswz; \
    bf16x8 va = *reinterpret_cast<const bf16x8*>(VTB + lq * 128 + voff); \
    bf16x8 vb = *reinterpret_cast<const bf16x8*>(VTB + (lq + 32) * 128 + voff); \
    y0 = __builtin_amdgcn_mfma_f32_32x32x16_bf16(va, pa.v, y0, 0, 0, 0); \
    y1 = __builtin_amdgcn_mfma_f32_32x32x16_bf16(vb, pa.v, y1, 0, 0, 0); \
}

__global__ __launch_bounds__(256)
void attn_mfma6(const unsigned short* __restrict__ QKV, unsigned short* __restrict__ Yb)
{
    __shared__ unsigned short Ks[64 * 64];    // [key][d], swizzled
    __shared__ unsigned short VTs[64 * 64];   // [d][key], swizzled
    __shared__ unsigned short Ysc[4][32 * 72];// per-wave [q][d], 144B stride

    const int tid = threadIdx.x, lane = tid & 63, wid = tid >> 6;
    const int lq = lane & 31, hi = lane >> 5;
    const int lqswz = (lq & 7) << 4;

    // XCD-grouped decomposition: id%8 == hb%8 -> same (h,b) shares an XCD
    const int id  = blockIdx.x;
    const int kk  = id >> 3;
    const int hb  = (id & 7) + 8 * (kk >> 3);
    const int pair = kk & 7;
    const int h = hb & 15, bz = hb >> 4;

    const size_t rowbase = (size_t)bz * TSEQ;
    const int hq = h * DHEAD, hk = 1024 + h * DHEAD, hv = 2048 + h * DHEAD;
    char* KsB = (char*)Ks;
    char* VTB = (char*)VTs;

    // staging thread mapping (constant per thread)
    const int krow = tid >> 3;           // K rows krow, krow+32
    const int kswz = ((tid & 7) * 16) ^ ((krow & 7) << 4);
    const int vk2  = 2 * (tid & 31);     // V key-pair
    const int vdg  = (tid >> 5) * 8;     // V d-group
    const int vkb  = vk2 * 2;            // byte offset of pair

    for (int iter = 0; iter < 2; ++iter) {
        const int qtile = iter ? (15 - pair) : pair;
        const int q0 = qtile * 128;
        const int wq = q0 + wid * 32;

        bf16x8 qf[4];                            // Q^T B-frags: d = 16s + 8hi + j
        {
            const unsigned short* qp = QKV + (rowbase + wq + lq) * QSTR + hq + hi * 8;
            #pragma unroll
            for (int s = 0; s < 4; ++s)
                qf[s] = *reinterpret_cast<const bf16x8*>(qp + s * 16);
        }
        f32x16 y0, y1;                           // Y^T tiles: d 0..31 / 32..63
        #pragma unroll
        for (int r = 0; r < 16; ++r) { y0[r] = 0.f; y1[r] = 0.f; }
        float mrow = NEG_BIG, lrow = 0.f;

        const int ktend = 2 * qtile + 2;

        // prefetch tile 0 into registers
        uint4 kr0, kr1, vr0, vr1;
        {
            const unsigned short* kp = QKV + (rowbase + krow) * QSTR + hk + (tid & 7) * 8;
            kr0 = *reinterpret_cast<const uint4*>(kp);
            kr1 = *reinterpret_cast<const uint4*>(kp + 32 * QSTR);
            const unsigned short* vp = QKV + (rowbase + vk2) * QSTR + hv + vdg;
            vr0 = *reinterpret_cast<const uint4*>(vp);
            vr1 = *reinterpret_cast<const uint4*>(vp + QSTR);
        }

        for (int kt = 0; kt < ktend; ++kt) {
            __syncthreads();                     // previous tile's consumers done
            // ---- write prefetched regs -> LDS (K swizzled, V^T perm-packed)
            *reinterpret_cast<uint4*>(KsB + krow * 128 + kswz) = kr0;
            *reinterpret_cast<uint4*>(KsB + (krow + 32) * 128 + kswz) = kr1;
            {
                unsigned pe, po;
                pe = __builtin_amdgcn_perm(vr1.x, vr0.x, 0x05040100u);
                po = __builtin_amdgcn_perm(vr1.x, vr0.x, 0x07060302u);
                *reinterpret_cast<unsigned*>(VTB + (vdg + 0) * 128 + (vkb ^ 0x00)) = pe;
                *reinterpret_cast<unsigned*>(VTB + (vdg + 1) * 128 + (vkb ^ 0x10)) = po;
                pe = __builtin_amdgcn_perm(vr1.y, vr0.y, 0x05040100u);
                po = __builtin_amdgcn_perm(vr1.y, vr0.y, 0x07060302u);
                *reinterpret_cast<unsigned*>(VTB + (vdg + 2) * 128 + (vkb ^ 0x20)) = pe;
                *reinterpret_cast<unsigned*>(VTB + (vdg + 3) * 128 + (vkb ^ 0x30)) = po;
                pe = __builtin_amdgcn_perm(vr1.z, vr0.z, 0x05040100u);
                po = __builtin_amdgcn_perm(vr1.z, vr0.z, 0x07060302u);
                *reinterpret_cast<unsigned*>(VTB + (vdg + 4) * 128 + (vkb ^ 0x40)) = pe;
                *reinterpret_cast<unsigned*>(VTB + (vdg + 5) * 128 + (vkb ^ 0x50)) = po;
                pe = __builtin_amdgcn_perm(vr1.w, vr0.w, 0x05040100u);
                po = __builtin_amdgcn_perm(vr1.w, vr0.w, 0x07060302u);
                *reinterpret_cast<unsigned*>(VTB + (vdg + 6) * 128 + (vkb ^ 0x60)) = pe;
                *reinterpret_cast<unsigned*>(VTB + (vdg + 7) * 128 + (vkb ^ 0x70)) = po;
            }
            __syncthreads();                     // LDS tile ready

            // ---- issue next tile's global loads (latency hides under compute)
            if (kt + 1 < ktend) {
                const unsigned short* kp = QKV + (rowbase + (kt + 1) * 64 + krow) * QSTR + hk + (tid & 7) * 8;
                kr0 = *reinterpret_cast<const uint4*>(kp);
                kr1 = *reinterpret_cast<const uint4*>(kp + 32 * QSTR);
                const unsigned short* vp = QKV + (rowbase + (kt + 1) * 64 + vk2) * QSTR + hv + vdg;
                vr0 = *reinterpret_cast<const uint4*>(vp);
                vr1 = *reinterpret_cast<const uint4*>(vp + QSTR);
            }

            if (kt * 64 > wq + 31) continue;     // tile above diagonal for this wave

            // ---- S^T = K Q^T (8 mfma 32x32x16); scale pre-folded into Q
            f32x16 s0, s1;
            #pragma unroll
            for (int r = 0; r < 16; ++r) { s0[r] = 0.f; s1[r] = 0.f; }
            #pragma unroll
            for (int s = 0; s < 4; ++s) {
                const int off = (s * 32 + hi * 16) ^ lqswz;
                bf16x8 k0 = *reinterpret_cast<const bf16x8*>(KsB + lq * 128 + off);
                bf16x8 k1 = *reinterpret_cast<const bf16x8*>(KsB + (lq + 32) * 128 + off);
                s0 = __builtin_amdgcn_mfma_f32_32x32x16_bf16(k0, qf[s], s0, 0, 0, 0);
                s1 = __builtin_amdgcn_mfma_f32_32x32x16_bf16(k1, qf[s], s1, 0, 0, 0);
            }

            // ---- causal mask (diagonal tiles only)
            const bool diag = (kt * 64 + 63) > wq;
            if (diag) {
                const int q_own = wq + lq;
                #pragma unroll
                for (int r = 0; r < 16; ++r) {
                    const int kl = kt * 64 + (r & 3) + 8 * (r >> 2) + 4 * hi;
                    if (kl > q_own) s0[r] = MASKVAL;
                    if (kl + 32 > q_own) s1[r] = MASKVAL;
                }
            }

            // ---- tree row max + pair exchange
            float t8[8];
            #pragma unroll
            for (int r = 0; r < 8; ++r)
                t8[r] = fmaxf(fmaxf(s0[r], s0[r + 8]), fmaxf(s1[r], s1[r + 8]));
            #pragma unroll
            for (int r = 0; r < 4; ++r) t8[r] = fmaxf(t8[r], t8[r + 4]);
            float pm = fmaxf(fmaxf(t8[0], t8[1]), fmaxf(t8[2], t8[3]));
            pm = fmaxf(pm, __shfl_xor(pm, 32));

            // ---- defer-max rescale (T13)
            if (__any(pm > mrow + DEFER_TH)) {
                const float mnew = fmaxf(mrow, pm);
                const float alpha = ex2(mrow - mnew);
                #pragma unroll
                for (int r = 0; r < 16; ++r) { y0[r] *= alpha; y1[r] *= alpha; }
                lrow *= alpha;
                mrow = mnew;
            }
            // ---- exp2 + tree row sum
            #pragma unroll
            for (int r = 0; r < 16; ++r) {
                s0[r] = ex2(s0[r] - mrow);
                s1[r] = ex2(s1[r] - mrow);
            }
            float a8[8];
            #pragma unroll
            for (int r = 0; r < 8; ++r) a8[r] = (s0[r] + s0[r + 8]) + (s1[r] + s1[r + 8]);
            #pragma unroll
            for (int r = 0; r < 4; ++r) a8[r] += a8[r + 4];
            float sum = (a8[0] + a8[1]) + (a8[2] + a8[3]);
            sum += __shfl_xor(sum, 32);
            lrow += sum;

            // ---- Y^T += V^T P^T (8 mfma); P^T frags via cvt_pk+permlane32_swap
            PV_STEP(0, s0, 0)
            PV_STEP(1, s0, 8)
            PV_STEP(2, s1, 0)
            PV_STEP(3, s1, 8)
        }

        // ---- epilogue: normalize, transpose via per-wave LDS, coalesced store
        {
            const float inv = 1.f / lrow;
            char* ysb = (char*)&Ysc[wid][0];
            #pragma unroll
            for (int t = 0; t < 8; ++t) {
                const int dl = ((2 * t) & 3) + 8 * (t >> 1) + 4 * hi;
                unsigned int wa = cvtpk(y0[2 * t] * inv, y0[2 * t + 1] * inv);
                unsigned int wb = cvtpk(y1[2 * t] * inv, y1[2 * t + 1] * inv);
                *reinterpret_cast<unsigned int*>(ysb + lq * 144 + dl * 2) = wa;
                *reinterpret_cast<unsigned int*>(ysb + lq * 144 + (dl + 32) * 2) = wb;
            }
            #pragma unroll
            for (int u = 0; u < 4; ++u) {
                const int rr = lane >> 1, ch = (lane & 1) + 2 * u;
                uint4 val = *reinterpret_cast<const uint4*>(ysb + rr * 144 + ch * 16);
                *reinterpret_cast<uint4*>(Yb + (rowbase + q0 + wid * 32 + rr) * CDIM + h * DHEAD + ch * 8) = val;
            }
        }
    }
}

// ---------------------------------------------------------------------------
extern "C" void kernel_launch(void* const* d_in, const int* in_sizes, int n_in,
                              void* d_out, int out_size, void* d_ws, size_t ws_size,
                              hipStream_t stream)
{
    const float* x  = (const float*)d_in[0];
    const float* Wk = (const float*)d_in[1];
    const float* bk = (const float*)d_in[2];
    const float* Wq = (const float*)d_in[3];
    const float* bq = (const float*)d_in[4];
    const float* Wv = (const float*)d_in[5];
    const float* bv = (const float*)d_in[6];
    const float* Wp = (const float*)d_in[7];
    const float* bp = (const float*)d_in[8];

    const size_t xe = (size_t)MROWS * CDIM;   // 8,388,608
    const size_t we = (size_t)CDIM * CDIM;    // 1,048,576
    unsigned short* xb    = (unsigned short*)d_ws;
    unsigned short* wqkvt = xb + xe;          // [3072][1024] = Wq^T|Wk^T|Wv^T
    unsigned short* wpt   = wqkvt + 3 * we;
    unsigned short* qkv   = wpt + we;         // [8192][3072] bf16
    unsigned short* ab    = qkv + (size_t)MROWS * QSTR;
    float*          bias3 = (float*)(ab + xe);

    cvt_x_kernel<<<(int)(xe / 8 / 256), 256, 0, stream>>>(x, xb);
    wt_kernel<<<dim3(32, 32, 4), 256, 0, stream>>>(
        Wq, Wk, Wv, Wp, wqkvt, wqkvt + we, wqkvt + 2 * we, wpt);
    pack_bias<<<12, 256, 0, stream>>>(bq, bk, bv, bias3);

    // fused QKV projection: 128x256 3-buf counted pipeline, 768 blocks (3 rounds)
    gemm_8ph3<128, 256, 0><<<768, 512, 0, stream>>>(xb, wqkvt, bias3, qkv,
                                                    QSTR, 1024);

    attn_mfma6<<<512, 256, 0, stream>>>(qkv, ab);

    // output projection -> fp32: 256x128 3-buf counted pipeline, 256 blocks (1 round)
    gemm_8ph3<256, 128, 1><<<256, 512, 0, stream>>>(ab, wpt, bp, d_out,
                                                    CDIM, 0);
}

// Round 15
// 163.903 us; speedup vs baseline: 1.3197x; 1.0171x over previous
//
#include <hip/hip_runtime.h>
#include <hip/hip_bf16.h>

#define CDIM   1024
#define NHEADS 16
#define DHEAD  64
#define BATCH  4
#define TSEQ   2048
#define MROWS  (BATCH * TSEQ)
#define QSTR   3072                /* fused qkv row stride */
#define NEG_BIG (-1e30f)
#define MASKVAL (-3.0e38f)
#define SCALE_L2E 0.18033688011f   /* 0.125 * log2(e) */
#define DEFER_TH 11.5416f          /* 8 nats in log2 units */

typedef __attribute__((ext_vector_type(8)))  short bf16x8;
typedef __attribute__((ext_vector_type(4)))  float f32x4;
typedef __attribute__((ext_vector_type(16))) float f32x16;

__device__ __forceinline__ unsigned short f2bf(float f) {
    __hip_bfloat16 h = __float2bfloat16(f);
    return *reinterpret_cast<unsigned short*>(&h);
}
__device__ __forceinline__ unsigned int cvtpk(float a, float b) {
    unsigned r;
    asm("v_cvt_pk_bf16_f32 %0, %1, %2" : "=v"(r) : "v"(a), "v"(b));
    return r;   // lo = bf16(a), hi = bf16(b)
}
__device__ __forceinline__ float ex2(float x) {   // raw v_exp_f32 (exp2)
    float r; asm("v_exp_f32 %0, %1" : "=v"(r) : "v"(x)); return r;
}

// ---------------- fused prep: x->bf16, 4x W->W^T bf16, bias concat ----------
// grid (32,32,8): z<4 -> W^T path (W[z] 32x32 LDS-transpose tiles);
// z>=4 -> cvt_x chunk (z-4); chunk 0 / y==0 / x<12 blocks also pack bias.
__global__ __launch_bounds__(256)
void prep_kernel(const float* __restrict__ x,
                 const float* __restrict__ Wq, const float* __restrict__ Wk,
                 const float* __restrict__ Wv, const float* __restrict__ Wp,
                 const float* __restrict__ bq, const float* __restrict__ bk,
                 const float* __restrict__ bv,
                 unsigned short* __restrict__ xb,
                 unsigned short* __restrict__ Tq, unsigned short* __restrict__ Tk,
                 unsigned short* __restrict__ Tv, unsigned short* __restrict__ Tp,
                 float* __restrict__ bias3)
{
    const int z = blockIdx.z, t = threadIdx.x;
    if (z < 4) {
        const float* W; unsigned short* T;
        switch (z) {
            case 0:  W = Wq; T = Tq; break;
            case 1:  W = Wk; T = Tk; break;
            case 2:  W = Wv; T = Tv; break;
            default: W = Wp; T = Tp; break;
        }
        __shared__ float tile[32][33];
        const int r = t >> 3;
        const int c4 = (t & 7) * 4;
        const int n0 = blockIdx.x * 32, k0 = blockIdx.y * 32;
        float4 v = *reinterpret_cast<const float4*>(&W[(size_t)(k0 + r) * CDIM + n0 + c4]);
        tile[r][c4 + 0] = v.x; tile[r][c4 + 1] = v.y;
        tile[r][c4 + 2] = v.z; tile[r][c4 + 3] = v.w;
        __syncthreads();
        uint2 o;
        o.x = (unsigned)f2bf(tile[c4 + 0][r]) | ((unsigned)f2bf(tile[c4 + 1][r]) << 16);
        o.y = (unsigned)f2bf(tile[c4 + 2][r]) | ((unsigned)f2bf(tile[c4 + 3][r]) << 16);
        *reinterpret_cast<uint2*>(&T[(size_t)(n0 + r) * CDIM + k0 + c4]) = o;
    } else {
        const int chunk = z - 4;
        size_t i = ((size_t)(chunk * 1024 + blockIdx.y * 32 + blockIdx.x) * 256 + t);
        const float4* p = reinterpret_cast<const float4*>(x) + i * 2;
        float4 a = p[0], b = p[1];
        uint4 o;
        o.x = (unsigned)f2bf(a.x) | ((unsigned)f2bf(a.y) << 16);
        o.y = (unsigned)f2bf(a.z) | ((unsigned)f2bf(a.w) << 16);
        o.z = (unsigned)f2bf(b.x) | ((unsigned)f2bf(b.y) << 16);
        o.w = (unsigned)f2bf(b.z) | ((unsigned)f2bf(b.w) << 16);
        *reinterpret_cast<uint4*>(xb + i * 8) = o;
        if (chunk == 0 && blockIdx.y == 0 && blockIdx.x < 12) {
            int j = blockIdx.x * 256 + t;   // 0..3071
            float v = (j < 1024) ? bq[j] : (j < 2048 ? bk[j - 1024] : bv[j - 2048]);
            bias3[j] = v;
        }
    }
}

// ======== 3-buffer counted-vmcnt pipelined GEMM (T3+T4, asym tiles) =========
// (R14-verified. See R14 comments for schedule derivation; vmcnt(6) counted.)
#define GBAR8  asm volatile("s_barrier" ::: "memory")
#define LGKM0  asm volatile("s_waitcnt lgkmcnt(0)" ::: "memory")
#define VMC6   asm volatile("s_waitcnt vmcnt(6)" ::: "memory")
#define VMC0   asm volatile("s_waitcnt vmcnt(0)" ::: "memory")

#define STAGE8(bufp, off, srcp) do { \
    __builtin_amdgcn_global_load_lds( \
        (const __attribute__((address_space(1))) void*)(srcp), \
        (__attribute__((address_space(3))) void*)((bufp) + (off) + wv * 1024), 16, 0, 0); \
    __builtin_amdgcn_global_load_lds( \
        (const __attribute__((address_space(1))) void*)((srcp) + 65536), \
        (__attribute__((address_space(3))) void*)((bufp) + (off) + 8192 + wv * 1024), 16, 0, 0); \
} while (0)

#define LDA_ALL(Ab) do { \
    _Pragma("unroll") for (int m_ = 0; m_ < 4; ++m_) { \
        const int rl_ = wr * 64 + m_ * 16 + lj; \
        _Pragma("unroll") for (int k_ = 0; k_ < 2; ++k_) \
            af[m_][k_] = *reinterpret_cast<const bf16x8*>( \
                (Ab) + rl_ * 128 + (((k_ * 4 + lg) ^ (lj & 7)) * 16)); \
    } } while (0)

#define LDB_PAIR(Bb, pairi) do { \
    _Pragma("unroll") for (int n_ = 0; n_ < 2; ++n_) { \
        const int rl_ = wc * 64 + ((pairi) * 2 + n_) * 16 + lj; \
        _Pragma("unroll") for (int k_ = 0; k_ < 2; ++k_) \
            bfr[n_][k_] = *reinterpret_cast<const bf16x8*>( \
                (Bb) + rl_ * 128 + (((k_ * 4 + lg) ^ (lj & 7)) * 16)); \
    } } while (0)

#define MM_PAIR(npair) do { \
    __builtin_amdgcn_s_setprio(1); \
    _Pragma("unroll") for (int m_ = 0; m_ < 4; ++m_) \
        _Pragma("unroll") for (int n_ = 0; n_ < 2; ++n_) \
            _Pragma("unroll") for (int k_ = 0; k_ < 2; ++k_) \
                acc[m_][(npair) * 2 + n_] = \
                    __builtin_amdgcn_mfma_f32_16x16x32_bf16( \
                        af[m_][k_], bfr[n_][k_], acc[m_][(npair) * 2 + n_], 0, 0, 0); \
    __builtin_amdgcn_s_setprio(0); \
} while (0)

template<int BM, int BN, int OUTMODE>
__global__ __launch_bounds__(512)
void gemm_8ph3(const unsigned short* __restrict__ A,
               const unsigned short* __restrict__ BT,
               const float* __restrict__ bias,
               void* __restrict__ Cout, int N, int nScaled)
{
    constexpr int WN = BN / 64;
    constexpr bool A_SMALL = (BM == 128);
    constexpr int AOFF = 0;
    constexpr int BOFF = BM * 128;
    constexpr int SOFF   = A_SMALL ? AOFF : BOFF;
    constexpr int LLOOFF = A_SMALL ? BOFF : AOFF;
    constexpr int LHIOFF = LLOOFF + 16384;
    constexpr int BUFSZ  = (BM + BN) * 128;     // 49152 bytes

    __shared__ __align__(16) char lds8[3 * BUFSZ];   // 144 KB
    const int tid = threadIdx.x;
    const int nbn = N / BN;
    const int bid = blockIdx.x;
    const int wg  = (bid & 7) * ((int)gridDim.x >> 3) + (bid >> 3);  // XCD swizzle
    const int n0  = (wg % nbn) * BN;
    const int m0  = (wg / nbn) * BM;

    const int lane = tid & 63, wv = tid >> 6;
    const int wr = wv / WN, wc = wv % WN;
    const int lj = lane & 15, lg = lane >> 4;
    const int srow = tid >> 3;
    const int gsw  = 8 * ((tid & 7) ^ ((tid >> 3) & 7));

    const unsigned short* Sm  = A_SMALL ? A : BT;
    const int             sb  = A_SMALL ? m0 : n0;
    const unsigned short* Lm  = A_SMALL ? BT : A;
    const int             lb  = A_SMALL ? n0 : m0;
    const unsigned short* Ss  = Sm + (size_t)(sb + srow) * 1024 + gsw;
    const unsigned short* Llo = Lm + (size_t)(lb + srow) * 1024 + gsw;
    const unsigned short* Lhi = Lm + (size_t)(lb + 128 + srow) * 1024 + gsw;

    f32x4 acc[4][4];
    #pragma unroll
    for (int i = 0; i < 4; ++i)
        #pragma unroll
        for (int j = 0; j < 4; ++j) acc[i][j] = f32x4{0.f, 0.f, 0.f, 0.f};

    char* bufA = &lds8[0];
    char* bufB = &lds8[BUFSZ];
    char* bufC = &lds8[2 * BUFSZ];

    STAGE8(bufA, SOFF,   Ss);
    STAGE8(bufA, LLOOFF, Llo);
    STAGE8(bufA, LHIOFF, Lhi);
    STAGE8(bufB, SOFF,   Ss  + 64);
    STAGE8(bufB, LLOOFF, Llo + 64);
    STAGE8(bufB, LHIOFF, Lhi + 64);
    VMC6; GBAR8;

    bf16x8 af[4][2], bfr[2][2];

    for (int t = 0; t < 16; ++t) {
        const bool st = (t + 2) < 16;
        const int  t2 = (t + 2) * 64;

        LDA_ALL(bufA + AOFF); LDB_PAIR(bufA + BOFF, 0);
        if (st) {
            STAGE8(bufC, SOFF,   Ss  + t2);
            STAGE8(bufC, LLOOFF, Llo + t2);
        }
        GBAR8; LGKM0; MM_PAIR(0); GBAR8;

        LDB_PAIR(bufA + BOFF, 1);
        if (st) STAGE8(bufC, LHIOFF, Lhi + t2);
        GBAR8; LGKM0; MM_PAIR(1);
        if (st) { VMC6; } else { VMC0; }
        GBAR8;

        char* tmp = bufA; bufA = bufB; bufB = bufC; bufC = tmp;
    }

    const float sc = (OUTMODE == 0 && n0 < nScaled) ? SCALE_L2E : 1.0f;
    float bcol[4];
    #pragma unroll
    for (int nr = 0; nr < 4; ++nr) bcol[nr] = bias[n0 + wc * 64 + nr * 16 + lj];

    #pragma unroll
    for (int mr = 0; mr < 4; ++mr) {
        #pragma unroll
        for (int r4 = 0; r4 < 4; ++r4) {
            const int row = m0 + wr * 64 + mr * 16 + lg * 4 + r4;
            #pragma unroll
            for (int nr = 0; nr < 4; ++nr) {
                const int col = n0 + wc * 64 + nr * 16 + lj;
                float v = (acc[mr][nr][r4] + bcol[nr]) * sc;
                if (OUTMODE == 0)
                    reinterpret_cast<unsigned short*>(Cout)[(size_t)row * N + col] = f2bf(v);
                else
                    reinterpret_cast<float*>(Cout)[(size_t)row * N + col] = v;
            }
        }
    }
}

// ---------------- MFMA flash attention (R9 skeleton + V-pack hoist) ---------
// 512 blocks, 4 waves x 32 q-rows; balanced pair (p, 15-p); XCD-grouped ids.
// V perm-pack moved from the serial write window to the END of the compute
// phase (load-waits already satisfied there; packing at load-issue would
// hoist the vmcnt wait and kill latency hiding). Write window = pure stores.
// DO NOT: __launch_bounds__ min-waves (R8 spill), KVBLK=128 (R12 spill),
// 1024-block remap (R11 dispatch), T15 2-deep S (R6 regs).
#define PV_STEP(m, T, rb) { \
    unsigned int w01 = cvtpk(T[(rb)+0], T[(rb)+1]); \
    unsigned int w23 = cvtpk(T[(rb)+2], T[(rb)+3]); \
    unsigned int w45 = cvtpk(T[(rb)+4], T[(rb)+5]); \
    unsigned int w67 = cvtpk(T[(rb)+6], T[(rb)+7]); \
    asm("v_permlane32_swap_b32 %0, %1" : "+v"(w01), "+v"(w45)); \
    asm("v_permlane32_swap_b32 %0, %1" : "+v"(w23), "+v"(w67)); \
    union { unsigned int u[4]; bf16x8 v; } pa; \
    pa.u[0] = w01; pa.u[1] = w23; pa.u[2] = w45; pa.u[3] = w67; \
    const int voff = (32 * (m) + 16 * hi) ^ lqswz; \
    bf16x8 va = *reinterpret_cast<const bf16x8*>(VTB + lq * 128 + voff); \
    bf16x8 vb = *reinterpret_cast<const bf16x8*>(VTB + (lq + 32) * 128 + voff); \
    y0 = __builtin_amdgcn_mfma_f32_32x32x16_bf16(va, pa.v, y0, 0, 0, 0); \
    y1 = __builtin_amdgcn_mfma_f32_32x32x16_bf16(vb, pa.v, y1, 0, 0, 0); \
}

#define VPACK() do { \
    pk[0] = __builtin_amdgcn_perm(vtb.x, vta.x, 0x05040100u); \
    pk[1] = __builtin_amdgcn_perm(vtb.x, vta.x, 0x07060302u); \
    pk[2] = __builtin_amdgcn_perm(vtb.y, vta.y, 0x05040100u); \
    pk[3] = __builtin_amdgcn_perm(vtb.y, vta.y, 0x07060302u); \
    pk[4] = __builtin_amdgcn_perm(vtb.z, vta.z, 0x05040100u); \
    pk[5] = __builtin_amdgcn_perm(vtb.z, vta.z, 0x07060302u); \
    pk[6] = __builtin_amdgcn_perm(vtb.w, vta.w, 0x05040100u); \
    pk[7] = __builtin_amdgcn_perm(vtb.w, vta.w, 0x07060302u); \
} while (0)

__global__ __launch_bounds__(256)
void attn_mfma6(const unsigned short* __restrict__ QKV, unsigned short* __restrict__ Yb)
{
    __shared__ unsigned short Ks[64 * 64];    // [key][d], swizzled
    __shared__ unsigned short VTs[64 * 64];   // [d][key], swizzled
    __shared__ unsigned short Ysc[4][32 * 72];// per-wave [q][d], 144B stride

    const int tid = threadIdx.x, lane = tid & 63, wid = tid >> 6;
    const int lq = lane & 31, hi = lane >> 5;
    const int lqswz = (lq & 7) << 4;

    // XCD-grouped decomposition: id%8 == hb%8 -> same (h,b) shares an XCD
    const int id  = blockIdx.x;
    const int kk  = id >> 3;
    const int hb  = (id & 7) + 8 * (kk >> 3);
    const int pair = kk & 7;
    const int h = hb & 15, bz = hb >> 4;

    const size_t rowbase = (size_t)bz * TSEQ;
    const int hq = h * DHEAD, hk = 1024 + h * DHEAD, hv = 2048 + h * DHEAD;
    char* KsB = (char*)Ks;
    char* VTB = (char*)VTs;

    // staging thread mapping (constant per thread)
    const int krow = tid >> 3;           // K rows krow, krow+32
    const int kswz = ((tid & 7) * 16) ^ ((krow & 7) << 4);
    const int vk2  = 2 * (tid & 31);     // V key-pair
    const int vdg  = (tid >> 5) * 8;     // V d-group
    const int vkb  = vk2 * 2;            // byte offset of pair

    for (int iter = 0; iter < 2; ++iter) {
        const int qtile = iter ? (15 - pair) : pair;
        const int q0 = qtile * 128;
        const int wq = q0 + wid * 32;

        bf16x8 qf[4];                            // Q^T B-frags: d = 16s + 8hi + j
        {
            const unsigned short* qp = QKV + (rowbase + wq + lq) * QSTR + hq + hi * 8;
            #pragma unroll
            for (int s = 0; s < 4; ++s)
                qf[s] = *reinterpret_cast<const bf16x8*>(qp + s * 16);
        }
        f32x16 y0, y1;                           // Y^T tiles: d 0..31 / 32..63
        #pragma unroll
        for (int r = 0; r < 16; ++r) { y0[r] = 0.f; y1[r] = 0.f; }
        float mrow = NEG_BIG, lrow = 0.f;

        const int ktend = 2 * qtile + 2;

        // prefetch tile 0 into registers; pack V immediately (prologue only)
        uint4 kr0, kr1, vta, vtb;
        unsigned pk[8];
        {
            const unsigned short* kp = QKV + (rowbase + krow) * QSTR + hk + (tid & 7) * 8;
            kr0 = *reinterpret_cast<const uint4*>(kp);
            kr1 = *reinterpret_cast<const uint4*>(kp + 32 * QSTR);
            const unsigned short* vp = QKV + (rowbase + vk2) * QSTR + hv + vdg;
            vta = *reinterpret_cast<const uint4*>(vp);
            vtb = *reinterpret_cast<const uint4*>(vp + QSTR);
            VPACK();
        }

        for (int kt = 0; kt < ktend; ++kt) {
            __syncthreads();                     // previous tile's consumers done
            // ---- write prefetched regs -> LDS (pure stores; packs pre-done)
            *reinterpret_cast<uint4*>(KsB + krow * 128 + kswz) = kr0;
            *reinterpret_cast<uint4*>(KsB + (krow + 32) * 128 + kswz) = kr1;
            #pragma unroll
            for (int i2 = 0; i2 < 8; ++i2) {
                const int d = vdg + i2;
                *reinterpret_cast<unsigned*>(VTB + d * 128 + (vkb ^ ((d & 7) << 4))) = pk[i2];
            }
            __syncthreads();                     // LDS tile ready

            // ---- issue next tile's global loads (latency hides under compute)
            const bool more = (kt + 1 < ktend);
            if (more) {
                const unsigned short* kp = QKV + (rowbase + (kt + 1) * 64 + krow) * QSTR + hk + (tid & 7) * 8;
                kr0 = *reinterpret_cast<const uint4*>(kp);
                kr1 = *reinterpret_cast<const uint4*>(kp + 32 * QSTR);
                const unsigned short* vp = QKV + (rowbase + (kt + 1) * 64 + vk2) * QSTR + hv + vdg;
                vta = *reinterpret_cast<const uint4*>(vp);
                vtb = *reinterpret_cast<const uint4*>(vp + QSTR);
            }

            if (kt * 64 <= wq + 31) {            // tile intersects this wave's rows
                // ---- S^T = K Q^T (8 mfma 32x32x16); scale pre-folded into Q
                f32x16 s0, s1;
                #pragma unroll
                for (int r = 0; r < 16; ++r) { s0[r] = 0.f; s1[r] = 0.f; }
                #pragma unroll
                for (int s = 0; s < 4; ++s) {
                    const int off = (s * 32 + hi * 16) ^ lqswz;
                    bf16x8 k0 = *reinterpret_cast<const bf16x8*>(KsB + lq * 128 + off);
                    bf16x8 k1 = *reinterpret_cast<const bf16x8*>(KsB + (lq + 32) * 128 + off);
                    s0 = __builtin_amdgcn_mfma_f32_32x32x16_bf16(k0, qf[s], s0, 0, 0, 0);
                    s1 = __builtin_amdgcn_mfma_f32_32x32x16_bf16(k1, qf[s], s1, 0, 0, 0);
                }

                // ---- causal mask (diagonal tiles only)
                const bool diag = (kt * 64 + 63) > wq;
                if (diag) {
                    const int q_own = wq + lq;
                    #pragma unroll
                    for (int r = 0; r < 16; ++r) {
                        const int kl = kt * 64 + (r & 3) + 8 * (r >> 2) + 4 * hi;
                        if (kl > q_own) s0[r] = MASKVAL;
                        if (kl + 32 > q_own) s1[r] = MASKVAL;
                    }
                }

                // ---- tree row max + pair exchange
                float t8[8];
                #pragma unroll
                for (int r = 0; r < 8; ++r)
                    t8[r] = fmaxf(fmaxf(s0[r], s0[r + 8]), fmaxf(s1[r], s1[r + 8]));
                #pragma unroll
                for (int r = 0; r < 4; ++r) t8[r] = fmaxf(t8[r], t8[r + 4]);
                float pm = fmaxf(fmaxf(t8[0], t8[1]), fmaxf(t8[2], t8[3]));
                pm = fmaxf(pm, __shfl_xor(pm, 32));

                // ---- defer-max rescale (T13)
                if (__any(pm > mrow + DEFER_TH)) {
                    const float mnew = fmaxf(mrow, pm);
                    const float alpha = ex2(mrow - mnew);
                    #pragma unroll
                    for (int r = 0; r < 16; ++r) { y0[r] *= alpha; y1[r] *= alpha; }
                    lrow *= alpha;
                    mrow = mnew;
                }
                // ---- exp2 + tree row sum
                #pragma unroll
                for (int r = 0; r < 16; ++r) {
                    s0[r] = ex2(s0[r] - mrow);
                    s1[r] = ex2(s1[r] - mrow);
                }
                float a8[8];
                #pragma unroll
                for (int r = 0; r < 8; ++r) a8[r] = (s0[r] + s0[r + 8]) + (s1[r] + s1[r + 8]);
                #pragma unroll
                for (int r = 0; r < 4; ++r) a8[r] += a8[r + 4];
                float sum = (a8[0] + a8[1]) + (a8[2] + a8[3]);
                sum += __shfl_xor(sum, 32);
                lrow += sum;

                // ---- Y^T += V^T P^T (8 mfma)
                PV_STEP(0, s0, 0)
                PV_STEP(1, s0, 8)
                PV_STEP(2, s1, 0)
                PV_STEP(3, s1, 8)
            }

            // ---- pack next tile's V here: load-waits are satisfied by now,
            //      and the packs leave the serial write window.
            if (more) VPACK();
        }

        // ---- epilogue: normalize, transpose via per-wave LDS, coalesced store
        {
            const float inv = 1.f / lrow;
            char* ysb = (char*)&Ysc[wid][0];
            #pragma unroll
            for (int t = 0; t < 8; ++t) {
                const int dl = ((2 * t) & 3) + 8 * (t >> 1) + 4 * hi;
                unsigned int wa = cvtpk(y0[2 * t] * inv, y0[2 * t + 1] * inv);
                unsigned int wb = cvtpk(y1[2 * t] * inv, y1[2 * t + 1] * inv);
                *reinterpret_cast<unsigned int*>(ysb + lq * 144 + dl * 2) = wa;
                *reinterpret_cast<unsigned int*>(ysb + lq * 144 + (dl + 32) * 2) = wb;
            }
            #pragma unroll
            for (int u = 0; u < 4; ++u) {
                const int rr = lane >> 1, ch = (lane & 1) + 2 * u;
                uint4 val = *reinterpret_cast<const uint4*>(ysb + rr * 144 + ch * 16);
                *reinterpret_cast<uint4*>(Yb + (rowbase + q0 + wid * 32 + rr) * CDIM + h * DHEAD + ch * 8) = val;
            }
        }
    }
}

// ---------------------------------------------------------------------------
extern "C" void kernel_launch(void* const* d_in, const int* in_sizes, int n_in,
                              void* d_out, int out_size, void* d_ws, size_t ws_size,
                              hipStream_t stream)
{
    const float* x  = (const float*)d_in[0];
    const float* Wk = (const float*)d_in[1];
    const float* bk = (const float*)d_in[2];
    const float* Wq = (const float*)d_in[3];
    const float* bq = (const float*)d_in[4];
    const float* Wv = (const float*)d_in[5];
    const float* bv = (const float*)d_in[6];
    const float* Wp = (const float*)d_in[7];
    const float* bp = (const float*)d_in[8];

    const size_t xe = (size_t)MROWS * CDIM;   // 8,388,608
    const size_t we = (size_t)CDIM * CDIM;    // 1,048,576
    unsigned short* xb    = (unsigned short*)d_ws;
    unsigned short* wqkvt = xb + xe;          // [3072][1024] = Wq^T|Wk^T|Wv^T
    unsigned short* wpt   = wqkvt + 3 * we;
    unsigned short* qkv   = wpt + we;         // [8192][3072] bf16
    unsigned short* ab    = qkv + (size_t)MROWS * QSTR;
    float*          bias3 = (float*)(ab + xe);

    // fused prep: x->bf16, W^T x4, bias concat (one launch)
    prep_kernel<<<dim3(32, 32, 8), 256, 0, stream>>>(
        x, Wq, Wk, Wv, Wp, bq, bk, bv,
        xb, wqkvt, wqkvt + we, wqkvt + 2 * we, wpt, bias3);

    // fused QKV projection: 128x256 3-buf counted pipeline, 768 blocks (3 rounds)
    gemm_8ph3<128, 256, 0><<<768, 512, 0, stream>>>(xb, wqkvt, bias3, qkv,
                                                    QSTR, 1024);

    attn_mfma6<<<512, 256, 0, stream>>>(qkv, ab);

    // output projection -> fp32: 256x128 3-buf counted pipeline, 256 blocks (1 round)
    gemm_8ph3<256, 128, 1><<<256, 512, 0, stream>>>(ab, wpt, bp, d_out,
                                                    CDIM, 0);
}

// Round 16
// 163.161 us; speedup vs baseline: 1.3258x; 1.0045x over previous
//
#include <hip/hip_runtime.h>
#include <hip/hip_bf16.h>

#define CDIM   1024
#define NHEADS 16
#define DHEAD  64
#define BATCH  4
#define TSEQ   2048
#define MROWS  (BATCH * TSEQ)
#define QSTR   3072                /* fused qkv row stride */
#define NEG_BIG (-1e30f)
#define MASKVAL (-3.0e38f)
#define SCALE_L2E 0.18033688011f   /* 0.125 * log2(e) */
#define DEFER_TH 11.5416f          /* 8 nats in log2 units */

typedef __attribute__((ext_vector_type(8)))  short bf16x8;
typedef __attribute__((ext_vector_type(4)))  float f32x4;
typedef __attribute__((ext_vector_type(16))) float f32x16;

__device__ __forceinline__ unsigned short f2bf(float f) {
    __hip_bfloat16 h = __float2bfloat16(f);
    return *reinterpret_cast<unsigned short*>(&h);
}
__device__ __forceinline__ unsigned int cvtpk(float a, float b) {
    unsigned r;
    asm("v_cvt_pk_bf16_f32 %0, %1, %2" : "=v"(r) : "v"(a), "v"(b));
    return r;   // lo = bf16(a), hi = bf16(b)
}
__device__ __forceinline__ float ex2(float x) {   // raw v_exp_f32 (exp2)
    float r; asm("v_exp_f32 %0, %1" : "=v"(r) : "v"(x)); return r;
}

// ---------------- fused prep: x->bf16, 4x W->W^T bf16, bias concat ----------
__global__ __launch_bounds__(256)
void prep_kernel(const float* __restrict__ x,
                 const float* __restrict__ Wq, const float* __restrict__ Wk,
                 const float* __restrict__ Wv, const float* __restrict__ Wp,
                 const float* __restrict__ bq, const float* __restrict__ bk,
                 const float* __restrict__ bv,
                 unsigned short* __restrict__ xb,
                 unsigned short* __restrict__ Tq, unsigned short* __restrict__ Tk,
                 unsigned short* __restrict__ Tv, unsigned short* __restrict__ Tp,
                 float* __restrict__ bias3)
{
    const int z = blockIdx.z, t = threadIdx.x;
    if (z < 4) {
        const float* W; unsigned short* T;
        switch (z) {
            case 0:  W = Wq; T = Tq; break;
            case 1:  W = Wk; T = Tk; break;
            case 2:  W = Wv; T = Tv; break;
            default: W = Wp; T = Tp; break;
        }
        __shared__ float tile[32][33];
        const int r = t >> 3;
        const int c4 = (t & 7) * 4;
        const int n0 = blockIdx.x * 32, k0 = blockIdx.y * 32;
        float4 v = *reinterpret_cast<const float4*>(&W[(size_t)(k0 + r) * CDIM + n0 + c4]);
        tile[r][c4 + 0] = v.x; tile[r][c4 + 1] = v.y;
        tile[r][c4 + 2] = v.z; tile[r][c4 + 3] = v.w;
        __syncthreads();
        uint2 o;
        o.x = (unsigned)f2bf(tile[c4 + 0][r]) | ((unsigned)f2bf(tile[c4 + 1][r]) << 16);
        o.y = (unsigned)f2bf(tile[c4 + 2][r]) | ((unsigned)f2bf(tile[c4 + 3][r]) << 16);
        *reinterpret_cast<uint2*>(&T[(size_t)(n0 + r) * CDIM + k0 + c4]) = o;
    } else {
        const int chunk = z - 4;
        size_t i = ((size_t)(chunk * 1024 + blockIdx.y * 32 + blockIdx.x) * 256 + t);
        const float4* p = reinterpret_cast<const float4*>(x) + i * 2;
        float4 a = p[0], b = p[1];
        uint4 o;
        o.x = (unsigned)f2bf(a.x) | ((unsigned)f2bf(a.y) << 16);
        o.y = (unsigned)f2bf(a.z) | ((unsigned)f2bf(a.w) << 16);
        o.z = (unsigned)f2bf(b.x) | ((unsigned)f2bf(b.y) << 16);
        o.w = (unsigned)f2bf(b.z) | ((unsigned)f2bf(b.w) << 16);
        *reinterpret_cast<uint4*>(xb + i * 8) = o;
        if (chunk == 0 && blockIdx.y == 0 && blockIdx.x < 12) {
            int j = blockIdx.x * 256 + t;   // 0..3071
            float v = (j < 1024) ? bq[j] : (j < 2048 ? bk[j - 1024] : bv[j - 2048]);
            bias3[j] = v;
        }
    }
}

// ======== 3-buffer counted-vmcnt pipelined GEMM (T3+T4, asym tiles) =========
// (R14-verified. vmcnt(6) counted; see R14 derivation.)
#define GBAR8  asm volatile("s_barrier" ::: "memory")
#define LGKM0  asm volatile("s_waitcnt lgkmcnt(0)" ::: "memory")
#define VMC6   asm volatile("s_waitcnt vmcnt(6)" ::: "memory")
#define VMC0   asm volatile("s_waitcnt vmcnt(0)" ::: "memory")

#define STAGE8(bufp, off, srcp) do { \
    __builtin_amdgcn_global_load_lds( \
        (const __attribute__((address_space(1))) void*)(srcp), \
        (__attribute__((address_space(3))) void*)((bufp) + (off) + wv * 1024), 16, 0, 0); \
    __builtin_amdgcn_global_load_lds( \
        (const __attribute__((address_space(1))) void*)((srcp) + 65536), \
        (__attribute__((address_space(3))) void*)((bufp) + (off) + 8192 + wv * 1024), 16, 0, 0); \
} while (0)

#define LDA_ALL(Ab) do { \
    _Pragma("unroll") for (int m_ = 0; m_ < 4; ++m_) { \
        const int rl_ = wr * 64 + m_ * 16 + lj; \
        _Pragma("unroll") for (int k_ = 0; k_ < 2; ++k_) \
            af[m_][k_] = *reinterpret_cast<const bf16x8*>( \
                (Ab) + rl_ * 128 + (((k_ * 4 + lg) ^ (lj & 7)) * 16)); \
    } } while (0)

#define LDB_PAIR(Bb, pairi) do { \
    _Pragma("unroll") for (int n_ = 0; n_ < 2; ++n_) { \
        const int rl_ = wc * 64 + ((pairi) * 2 + n_) * 16 + lj; \
        _Pragma("unroll") for (int k_ = 0; k_ < 2; ++k_) \
            bfr[n_][k_] = *reinterpret_cast<const bf16x8*>( \
                (Bb) + rl_ * 128 + (((k_ * 4 + lg) ^ (lj & 7)) * 16)); \
    } } while (0)

#define MM_PAIR(npair) do { \
    __builtin_amdgcn_s_setprio(1); \
    _Pragma("unroll") for (int m_ = 0; m_ < 4; ++m_) \
        _Pragma("unroll") for (int n_ = 0; n_ < 2; ++n_) \
            _Pragma("unroll") for (int k_ = 0; k_ < 2; ++k_) \
                acc[m_][(npair) * 2 + n_] = \
                    __builtin_amdgcn_mfma_f32_16x16x32_bf16( \
                        af[m_][k_], bfr[n_][k_], acc[m_][(npair) * 2 + n_], 0, 0, 0); \
    __builtin_amdgcn_s_setprio(0); \
} while (0)

template<int BM, int BN, int OUTMODE>
__global__ __launch_bounds__(512)
void gemm_8ph3(const unsigned short* __restrict__ A,
               const unsigned short* __restrict__ BT,
               const float* __restrict__ bias,
               void* __restrict__ Cout, int N, int nScaled)
{
    constexpr int WN = BN / 64;
    constexpr bool A_SMALL = (BM == 128);
    constexpr int AOFF = 0;
    constexpr int BOFF = BM * 128;
    constexpr int SOFF   = A_SMALL ? AOFF : BOFF;
    constexpr int LLOOFF = A_SMALL ? BOFF : AOFF;
    constexpr int LHIOFF = LLOOFF + 16384;
    constexpr int BUFSZ  = (BM + BN) * 128;     // 49152 bytes

    __shared__ __align__(16) char lds8[3 * BUFSZ];   // 144 KB
    const int tid = threadIdx.x;
    const int nbn = N / BN;
    const int bid = blockIdx.x;
    const int wg  = (bid & 7) * ((int)gridDim.x >> 3) + (bid >> 3);  // XCD swizzle
    const int n0  = (wg % nbn) * BN;
    const int m0  = (wg / nbn) * BM;

    const int lane = tid & 63, wv = tid >> 6;
    const int wr = wv / WN, wc = wv % WN;
    const int lj = lane & 15, lg = lane >> 4;
    const int srow = tid >> 3;
    const int gsw  = 8 * ((tid & 7) ^ ((tid >> 3) & 7));

    const unsigned short* Sm  = A_SMALL ? A : BT;
    const int             sb  = A_SMALL ? m0 : n0;
    const unsigned short* Lm  = A_SMALL ? BT : A;
    const int             lb  = A_SMALL ? n0 : m0;
    const unsigned short* Ss  = Sm + (size_t)(sb + srow) * 1024 + gsw;
    const unsigned short* Llo = Lm + (size_t)(lb + srow) * 1024 + gsw;
    const unsigned short* Lhi = Lm + (size_t)(lb + 128 + srow) * 1024 + gsw;

    f32x4 acc[4][4];
    #pragma unroll
    for (int i = 0; i < 4; ++i)
        #pragma unroll
        for (int j = 0; j < 4; ++j) acc[i][j] = f32x4{0.f, 0.f, 0.f, 0.f};

    char* bufA = &lds8[0];
    char* bufB = &lds8[BUFSZ];
    char* bufC = &lds8[2 * BUFSZ];

    STAGE8(bufA, SOFF,   Ss);
    STAGE8(bufA, LLOOFF, Llo);
    STAGE8(bufA, LHIOFF, Lhi);
    STAGE8(bufB, SOFF,   Ss  + 64);
    STAGE8(bufB, LLOOFF, Llo + 64);
    STAGE8(bufB, LHIOFF, Lhi + 64);
    VMC6; GBAR8;

    bf16x8 af[4][2], bfr[2][2];

    for (int t = 0; t < 16; ++t) {
        const bool st = (t + 2) < 16;
        const int  t2 = (t + 2) * 64;

        LDA_ALL(bufA + AOFF); LDB_PAIR(bufA + BOFF, 0);
        if (st) {
            STAGE8(bufC, SOFF,   Ss  + t2);
            STAGE8(bufC, LLOOFF, Llo + t2);
        }
        GBAR8; LGKM0; MM_PAIR(0); GBAR8;

        LDB_PAIR(bufA + BOFF, 1);
        if (st) STAGE8(bufC, LHIOFF, Lhi + t2);
        GBAR8; LGKM0; MM_PAIR(1);
        if (st) { VMC6; } else { VMC0; }
        GBAR8;

        char* tmp = bufA; bufA = bufB; bufB = bufC; bufC = tmp;
    }

    const float sc = (OUTMODE == 0 && n0 < nScaled) ? SCALE_L2E : 1.0f;
    float bcol[4];
    #pragma unroll
    for (int nr = 0; nr < 4; ++nr) bcol[nr] = bias[n0 + wc * 64 + nr * 16 + lj];

    #pragma unroll
    for (int mr = 0; mr < 4; ++mr) {
        #pragma unroll
        for (int r4 = 0; r4 < 4; ++r4) {
            const int row = m0 + wr * 64 + mr * 16 + lg * 4 + r4;
            #pragma unroll
            for (int nr = 0; nr < 4; ++nr) {
                const int col = n0 + wc * 64 + nr * 16 + lj;
                float v = (acc[mr][nr][r4] + bcol[nr]) * sc;
                if (OUTMODE == 0)
                    reinterpret_cast<unsigned short*>(Cout)[(size_t)row * N + col] = f2bf(v);
                else
                    reinterpret_cast<float*>(Cout)[(size_t)row * N + col] = v;
            }
        }
    }
}

// ---------------- MFMA flash attention: K/V dbuf, ONE barrier/tile ----------
// R15 body + LDS double-buffer. Race analysis: write(kt) targets KV[kt&1],
// whose last readers ran at compute(kt-2). Per-wave order is
// ... compute(kt-2), write(kt-1), BARRIER(kt-1), compute(kt-1), write(kt) ...
// so any wave reaching write(kt) has passed BARRIER(kt-1), which all waves
// reach only after their compute(kt-2) -> no WAR race with a single barrier.
// Outer-pair boundary: ktend even => last tile reads KV[1]; the next q-tile's
// first write hits KV[0]; its BARRIER(0) precedes the write of KV[1] at kt=1,
// and all waves pass BARRIER(0) only after finishing the prior epilogue.
// LDS 51200B -> 2 blocks/CU (grid-limited anyway). DO NOT: min-waves bound
// (R8 spill), KVBLK=128 (R12 spill), 1024-block remap (R11), 2-deep S (R6).
#define PV_STEP(m, T, rb) { \
    unsigned int w01 = cvtpk(T[(rb)+0], T[(rb)+1]); \
    unsigned int w23 = cvtpk(T[(rb)+2], T[(rb)+3]); \
    unsigned int w45 = cvtpk(T[(rb)+4], T[(rb)+5]); \
    unsigned int w67 = cvtpk(T[(rb)+6], T[(rb)+7]); \
    asm("v_permlane32_swap_b32 %0, %1" : "+v"(w01), "+v"(w45)); \
    asm("v_permlane32_swap_b32 %0, %1" : "+v"(w23), "+v"(w67)); \
    union { unsigned int u[4]; bf16x8 v; } pa; \
    pa.u[0] = w01; pa.u[1] = w23; pa.u[2] = w45; pa.u[3] = w67; \
    const int voff = (32 * (m) + 16 * hi) ^ lqswz; \
    bf16x8 va = *reinterpret_cast<const bf16x8*>(VTB + lq * 128 + voff); \
    bf16x8 vb = *reinterpret_cast<const bf16x8*>(VTB + (lq + 32) * 128 + voff); \
    y0 = __builtin_amdgcn_mfma_f32_32x32x16_bf16(va, pa.v, y0, 0, 0, 0); \
    y1 = __builtin_amdgcn_mfma_f32_32x32x16_bf16(vb, pa.v, y1, 0, 0, 0); \
}

#define VPACK() do { \
    pk[0] = __builtin_amdgcn_perm(vtb.x, vta.x, 0x05040100u); \
    pk[1] = __builtin_amdgcn_perm(vtb.x, vta.x, 0x07060302u); \
    pk[2] = __builtin_amdgcn_perm(vtb.y, vta.y, 0x05040100u); \
    pk[3] = __builtin_amdgcn_perm(vtb.y, vta.y, 0x07060302u); \
    pk[4] = __builtin_amdgcn_perm(vtb.z, vta.z, 0x05040100u); \
    pk[5] = __builtin_amdgcn_perm(vtb.z, vta.z, 0x07060302u); \
    pk[6] = __builtin_amdgcn_perm(vtb.w, vta.w, 0x05040100u); \
    pk[7] = __builtin_amdgcn_perm(vtb.w, vta.w, 0x07060302u); \
} while (0)

__global__ __launch_bounds__(256)
void attn_mfma6(const unsigned short* __restrict__ QKV, unsigned short* __restrict__ Yb)
{
    __shared__ __align__(16) char KV[2][16384];   // [buf][K 8KB | V^T 8KB]
    __shared__ unsigned short Ysc[4][32 * 72];    // per-wave [q][d], 144B stride

    const int tid = threadIdx.x, lane = tid & 63, wid = tid >> 6;
    const int lq = lane & 31, hi = lane >> 5;
    const int lqswz = (lq & 7) << 4;

    // XCD-grouped decomposition: id%8 == hb%8 -> same (h,b) shares an XCD
    const int id  = blockIdx.x;
    const int kk  = id >> 3;
    const int hb  = (id & 7) + 8 * (kk >> 3);
    const int pair = kk & 7;
    const int h = hb & 15, bz = hb >> 4;

    const size_t rowbase = (size_t)bz * TSEQ;
    const int hq = h * DHEAD, hk = 1024 + h * DHEAD, hv = 2048 + h * DHEAD;

    // staging thread mapping (constant per thread)
    const int krow = tid >> 3;           // K rows krow, krow+32
    const int kswz = ((tid & 7) * 16) ^ ((krow & 7) << 4);
    const int vk2  = 2 * (tid & 31);     // V key-pair
    const int vdg  = (tid >> 5) * 8;     // V d-group
    const int vkb  = vk2 * 2;            // byte offset of pair

    for (int iter = 0; iter < 2; ++iter) {
        const int qtile = iter ? (15 - pair) : pair;
        const int q0 = qtile * 128;
        const int wq = q0 + wid * 32;

        bf16x8 qf[4];                            // Q^T B-frags: d = 16s + 8hi + j
        {
            const unsigned short* qp = QKV + (rowbase + wq + lq) * QSTR + hq + hi * 8;
            #pragma unroll
            for (int s = 0; s < 4; ++s)
                qf[s] = *reinterpret_cast<const bf16x8*>(qp + s * 16);
        }
        f32x16 y0, y1;                           // Y^T tiles: d 0..31 / 32..63
        #pragma unroll
        for (int r = 0; r < 16; ++r) { y0[r] = 0.f; y1[r] = 0.f; }
        float mrow = NEG_BIG, lrow = 0.f;

        const int ktend = 2 * qtile + 2;

        // prefetch tile 0 into registers; pack V immediately (prologue only)
        uint4 kr0, kr1, vta, vtb;
        unsigned pk[8];
        {
            const unsigned short* kp = QKV + (rowbase + krow) * QSTR + hk + (tid & 7) * 8;
            kr0 = *reinterpret_cast<const uint4*>(kp);
            kr1 = *reinterpret_cast<const uint4*>(kp + 32 * QSTR);
            const unsigned short* vp = QKV + (rowbase + vk2) * QSTR + hv + vdg;
            vta = *reinterpret_cast<const uint4*>(vp);
            vtb = *reinterpret_cast<const uint4*>(vp + QSTR);
            VPACK();
        }

        for (int kt = 0; kt < ktend; ++kt) {
            char* KsB = &KV[kt & 1][0];
            char* VTB = &KV[kt & 1][8192];
            // ---- write prefetched regs -> buf[kt&1] (no pre-barrier: dbuf)
            *reinterpret_cast<uint4*>(KsB + krow * 128 + kswz) = kr0;
            *reinterpret_cast<uint4*>(KsB + (krow + 32) * 128 + kswz) = kr1;
            #pragma unroll
            for (int i2 = 0; i2 < 8; ++i2) {
                const int d = vdg + i2;
                *reinterpret_cast<unsigned*>(VTB + d * 128 + (vkb ^ ((d & 7) << 4))) = pk[i2];
            }
            __syncthreads();                     // single barrier per tile

            // ---- issue next tile's global loads (latency hides under compute)
            const bool more = (kt + 1 < ktend);
            if (more) {
                const unsigned short* kp = QKV + (rowbase + (kt + 1) * 64 + krow) * QSTR + hk + (tid & 7) * 8;
                kr0 = *reinterpret_cast<const uint4*>(kp);
                kr1 = *reinterpret_cast<const uint4*>(kp + 32 * QSTR);
                const unsigned short* vp = QKV + (rowbase + (kt + 1) * 64 + vk2) * QSTR + hv + vdg;
                vta = *reinterpret_cast<const uint4*>(vp);
                vtb = *reinterpret_cast<const uint4*>(vp + QSTR);
            }

            if (kt * 64 <= wq + 31) {            // tile intersects this wave's rows
                // ---- S^T = K Q^T (8 mfma 32x32x16); scale pre-folded into Q
                f32x16 s0, s1;
                #pragma unroll
                for (int r = 0; r < 16; ++r) { s0[r] = 0.f; s1[r] = 0.f; }
                #pragma unroll
                for (int s = 0; s < 4; ++s) {
                    const int off = (s * 32 + hi * 16) ^ lqswz;
                    bf16x8 k0 = *reinterpret_cast<const bf16x8*>(KsB + lq * 128 + off);
                    bf16x8 k1 = *reinterpret_cast<const bf16x8*>(KsB + (lq + 32) * 128 + off);
                    s0 = __builtin_amdgcn_mfma_f32_32x32x16_bf16(k0, qf[s], s0, 0, 0, 0);
                    s1 = __builtin_amdgcn_mfma_f32_32x32x16_bf16(k1, qf[s], s1, 0, 0, 0);
                }

                // ---- causal mask (diagonal tiles only)
                const bool diag = (kt * 64 + 63) > wq;
                if (diag) {
                    const int q_own = wq + lq;
                    #pragma unroll
                    for (int r = 0; r < 16; ++r) {
                        const int kl = kt * 64 + (r & 3) + 8 * (r >> 2) + 4 * hi;
                        if (kl > q_own) s0[r] = MASKVAL;
                        if (kl + 32 > q_own) s1[r] = MASKVAL;
                    }
                }

                // ---- tree row max + pair exchange
                float t8[8];
                #pragma unroll
                for (int r = 0; r < 8; ++r)
                    t8[r] = fmaxf(fmaxf(s0[r], s0[r + 8]), fmaxf(s1[r], s1[r + 8]));
                #pragma unroll
                for (int r = 0; r < 4; ++r) t8[r] = fmaxf(t8[r], t8[r + 4]);
                float pm = fmaxf(fmaxf(t8[0], t8[1]), fmaxf(t8[2], t8[3]));
                pm = fmaxf(pm, __shfl_xor(pm, 32));

                // ---- defer-max rescale (T13)
                if (__any(pm > mrow + DEFER_TH)) {
                    const float mnew = fmaxf(mrow, pm);
                    const float alpha = ex2(mrow - mnew);
                    #pragma unroll
                    for (int r = 0; r < 16; ++r) { y0[r] *= alpha; y1[r] *= alpha; }
                    lrow *= alpha;
                    mrow = mnew;
                }
                // ---- exp2 + tree row sum
                #pragma unroll
                for (int r = 0; r < 16; ++r) {
                    s0[r] = ex2(s0[r] - mrow);
                    s1[r] = ex2(s1[r] - mrow);
                }
                float a8[8];
                #pragma unroll
                for (int r = 0; r < 8; ++r) a8[r] = (s0[r] + s0[r + 8]) + (s1[r] + s1[r + 8]);
                #pragma unroll
                for (int r = 0; r < 4; ++r) a8[r] += a8[r + 4];
                float sum = (a8[0] + a8[1]) + (a8[2] + a8[3]);
                sum += __shfl_xor(sum, 32);
                lrow += sum;

                // ---- Y^T += V^T P^T (8 mfma)
                PV_STEP(0, s0, 0)
                PV_STEP(1, s0, 8)
                PV_STEP(2, s1, 0)
                PV_STEP(3, s1, 8)
            }

            // ---- pack next tile's V (load-waits satisfied; outside write window)
            if (more) VPACK();
        }

        // ---- epilogue: normalize, transpose via per-wave LDS, coalesced store
        {
            const float inv = 1.f / lrow;
            char* ysb = (char*)&Ysc[wid][0];
            #pragma unroll
            for (int t = 0; t < 8; ++t) {
                const int dl = ((2 * t) & 3) + 8 * (t >> 1) + 4 * hi;
                unsigned int wa = cvtpk(y0[2 * t] * inv, y0[2 * t + 1] * inv);
                unsigned int wb = cvtpk(y1[2 * t] * inv, y1[2 * t + 1] * inv);
                *reinterpret_cast<unsigned int*>(ysb + lq * 144 + dl * 2) = wa;
                *reinterpret_cast<unsigned int*>(ysb + lq * 144 + (dl + 32) * 2) = wb;
            }
            #pragma unroll
            for (int u = 0; u < 4; ++u) {
                const int rr = lane >> 1, ch = (lane & 1) + 2 * u;
                uint4 val = *reinterpret_cast<const uint4*>(ysb + rr * 144 + ch * 16);
                *reinterpret_cast<uint4*>(Yb + (rowbase + q0 + wid * 32 + rr) * CDIM + h * DHEAD + ch * 8) = val;
            }
        }
    }
}

// ---------------------------------------------------------------------------
extern "C" void kernel_launch(void* const* d_in, const int* in_sizes, int n_in,
                              void* d_out, int out_size, void* d_ws, size_t ws_size,
                              hipStream_t stream)
{
    const float* x  = (const float*)d_in[0];
    const float* Wk = (const float*)d_in[1];
    const float* bk = (const float*)d_in[2];
    const float* Wq = (const float*)d_in[3];
    const float* bq = (const float*)d_in[4];
    const float* Wv = (const float*)d_in[5];
    const float* bv = (const float*)d_in[6];
    const float* Wp = (const float*)d_in[7];
    const float* bp = (const float*)d_in[8];

    const size_t xe = (size_t)MROWS * CDIM;   // 8,388,608
    const size_t we = (size_t)CDIM * CDIM;    // 1,048,576
    unsigned short* xb    = (unsigned short*)d_ws;
    unsigned short* wqkvt = xb + xe;          // [3072][1024] = Wq^T|Wk^T|Wv^T
    unsigned short* wpt   = wqkvt + 3 * we;
    unsigned short* qkv   = wpt + we;         // [8192][3072] bf16
    unsigned short* ab    = qkv + (size_t)MROWS * QSTR;
    float*          bias3 = (float*)(ab + xe);

    // fused prep: x->bf16, W^T x4, bias concat (one launch)
    prep_kernel<<<dim3(32, 32, 8), 256, 0, stream>>>(
        x, Wq, Wk, Wv, Wp, bq, bk, bv,
        xb, wqkvt, wqkvt + we, wqkvt + 2 * we, wpt, bias3);

    // fused QKV projection: 128x256 3-buf counted pipeline, 768 blocks (3 rounds)
    gemm_8ph3<128, 256, 0><<<768, 512, 0, stream>>>(xb, wqkvt, bias3, qkv,
                                                    QSTR, 1024);

    attn_mfma6<<<512, 256, 0, stream>>>(qkv, ab);

    // output projection -> fp32: 256x128 3-buf counted pipeline, 256 blocks (1 round)
    gemm_8ph3<256, 128, 1><<<256, 512, 0, stream>>>(ab, wpt, bp, d_out,
                                                    CDIM, 0);
}